// Round 2
// baseline (16749.907 us; speedup 1.0000x reference)
//
#include <hip/hip_runtime.h>
#include <stdint.h>

typedef __bf16 bf16x8 __attribute__((ext_vector_type(8)));
typedef float f32x4 __attribute__((ext_vector_type(4)));

__device__ __forceinline__ unsigned short f2bf(float f) {
    union { float f; unsigned u; } v; v.f = f;
    unsigned u = v.u;
    unsigned r = u + 0x7fffu + ((u >> 16) & 1u);
    return (unsigned short)(r >> 16);
}
__device__ __forceinline__ float bf2f(unsigned short s) {
    union { unsigned u; float f; } v; v.u = ((unsigned)s) << 16; return v.f;
}

// ---------------- W conversion: stack [W_bond; W_vin; W_vconn] as bf16 [1536][512]
// plus lo-residual for W_vconn (split precision)
__global__ __launch_bounds__(256) void k_convert_w(
    const float* __restrict__ Wb, const float* __restrict__ Wv,
    const float* __restrict__ Wc, unsigned short* __restrict__ Wbf,
    unsigned short* __restrict__ Wlo)
{
    int idx = blockIdx.x * 256 + threadIdx.x;
    if (idx >= 1536 * 512) return;
    int m = idx >> 9, k = idx & 511;
    float s;
    if (m < 512)       s = Wb[m * 512 + k];
    else if (m < 1024) s = Wv[(m - 512) * 512 + k];
    else               s = Wc[(m - 1024) * 512 + k];
    unsigned short hi = f2bf(s);
    Wbf[idx] = hi;
    if (m >= 1024) Wlo[(size_t)(m - 1024) * 512 + k] = f2bf(s - bf2f(hi));
}

// ---------------- degree init / count / finish
__global__ __launch_bounds__(256) void k_init_deg(float* degb, float* degv, int N) {
    int n = blockIdx.x * 256 + threadIdx.x;
    if (n < N) { degb[n] = 1.0f; degv[n] = 0.0f; }  // bond deg starts at 1 (self loop)
}
__global__ __launch_bounds__(256) void k_count(const int* __restrict__ rows, int E, float* deg) {
    int e = blockIdx.x * 256 + threadIdx.x;
    if (e < E) unsafeAtomicAdd(deg + rows[e], 1.0f);
}
__global__ __launch_bounds__(256) void k_finish_deg(
    const float* __restrict__ degb, const float* __restrict__ degv,
    float* __restrict__ dinv, float* __restrict__ vs, int N)
{
    int n = blockIdx.x * 256 + threadIdx.x;
    if (n < N) {
        dinv[n] = rsqrtf(degb[n]);              // deg >= 1 always
        vs[n]   = 1.0f / fmaxf(degv[n], 1.0f);  // clip(deg,1)
    }
}

// ---------------- GEMM (bond|vin): Y[n,m] = sum_k x[n,k] * Wst[m,k]
// 128x128 tile, BK=64, 4 waves (2x2), 16x16x32 bf16 MFMA, XOR-swizzled LDS.
__global__ __launch_bounds__(256) void k_gemm(
    const float* __restrict__ x, const unsigned short* __restrict__ Wbf,
    unsigned short* __restrict__ Ybv, int N)
{
    __shared__ uint4 As[1024];  // [row][k8swz]  row*8 + (k8 ^ (row&7))
    __shared__ uint4 Bs[1024];

    const int t = threadIdx.x;
    const int bm = blockIdx.x, bn = blockIdx.y;
    const int row = t >> 1, half = t & 1;
    const int ga = bm * 128 + row;   // x row
    const int gb = bn * 128 + row;   // stacked-W row (0..1023)
    const int lane = t & 63;
    const int w = t >> 6;
    const int wr = w >> 1, wc = w & 1;

    f32x4 acc[4][4];
    #pragma unroll
    for (int i = 0; i < 4; i++)
        #pragma unroll
        for (int j = 0; j < 4; j++) acc[i][j] = (f32x4){0.f, 0.f, 0.f, 0.f};

    for (int kt = 0; kt < 512; kt += 64) {
        const float4* ax = (const float4*)(x + (size_t)ga * 512 + kt + half * 32);
        #pragma unroll
        for (int c = 0; c < 4; c++) {
            float4 f0, f1;
            if (ga < N) { f0 = ax[c * 2]; f1 = ax[c * 2 + 1]; }
            else { f0 = make_float4(0.f, 0.f, 0.f, 0.f); f1 = f0; }
            uint4 p;
            p.x = (unsigned)f2bf(f0.x) | ((unsigned)f2bf(f0.y) << 16);
            p.y = (unsigned)f2bf(f0.z) | ((unsigned)f2bf(f0.w) << 16);
            p.z = (unsigned)f2bf(f1.x) | ((unsigned)f2bf(f1.y) << 16);
            p.w = (unsigned)f2bf(f1.z) | ((unsigned)f2bf(f1.w) << 16);
            int k8 = half * 4 + c;
            As[row * 8 + (k8 ^ (row & 7))] = p;
        }
        const uint4* bw = (const uint4*)(Wbf + (size_t)gb * 512 + kt + half * 32);
        #pragma unroll
        for (int c = 0; c < 4; c++) {
            uint4 p = bw[c];
            int k8 = half * 4 + c;
            Bs[row * 8 + (k8 ^ (row & 7))] = p;
        }
        __syncthreads();
        #pragma unroll
        for (int kk = 0; kk < 2; kk++) {
            bf16x8 a[4], b[4];
            #pragma unroll
            for (int ni = 0; ni < 4; ni++) {
                int ar = wr * 64 + ni * 16 + (lane & 15);
                int k8 = kk * 4 + (lane >> 4);
                a[ni] = __builtin_bit_cast(bf16x8, As[ar * 8 + (k8 ^ (ar & 7))]);
            }
            #pragma unroll
            for (int mi = 0; mi < 4; mi++) {
                int br = wc * 64 + mi * 16 + (lane & 15);
                int k8 = kk * 4 + (lane >> 4);
                b[mi] = __builtin_bit_cast(bf16x8, Bs[br * 8 + (k8 ^ (br & 7))]);
            }
            #pragma unroll
            for (int mi = 0; mi < 4; mi++)
                #pragma unroll
                for (int ni = 0; ni < 4; ni++)
                    acc[mi][ni] = __builtin_amdgcn_mfma_f32_16x16x32_bf16(
                        a[ni], b[mi], acc[mi][ni], 0, 0, 0);
        }
        __syncthreads();
    }

    // epilogue: D row=(lane>>4)*4+j (n), col=lane&15 (m)
    const int nbase = bm * 128 + wr * 64 + (lane >> 4) * 4;
    const int mbase = bn * 128 + wc * 64 + (lane & 15);
    #pragma unroll
    for (int mi = 0; mi < 4; mi++) {
        int m = mbase + mi * 16;
        #pragma unroll
        for (int ni = 0; ni < 4; ni++) {
            int n0 = nbase + ni * 16;
            #pragma unroll
            for (int j = 0; j < 4; j++)
                Ybv[(size_t)(n0 + j) * 1024 + m] = f2bf(acc[mi][ni][j]);
        }
    }
}

// ---------------- GEMM (vconn, split-precision): Yc[n,m] f32
// x = xh + xl, W = wh + wl (bf16 pairs); acc += xh*wh + xl*wh + xh*wl
__global__ __launch_bounds__(256) void k_gemm_split(
    const float* __restrict__ x, const unsigned short* __restrict__ Wbf,
    const unsigned short* __restrict__ Wlo, float* __restrict__ Yc, int N)
{
    __shared__ uint4 Ah[1024], Al[1024], Bh[1024], Bl[1024];

    const int t = threadIdx.x;
    const int bm = blockIdx.x, bn = blockIdx.y;  // bn in [0,4)
    const int row = t >> 1, half = t & 1;
    const int ga = bm * 128 + row;
    const int gb = bn * 128 + row;               // 0..511 (vconn row)
    const int lane = t & 63;
    const int w = t >> 6;
    const int wr = w >> 1, wc = w & 1;

    f32x4 acc[4][4];
    #pragma unroll
    for (int i = 0; i < 4; i++)
        #pragma unroll
        for (int j = 0; j < 4; j++) acc[i][j] = (f32x4){0.f, 0.f, 0.f, 0.f};

    for (int kt = 0; kt < 512; kt += 64) {
        const float4* ax = (const float4*)(x + (size_t)ga * 512 + kt + half * 32);
        #pragma unroll
        for (int c = 0; c < 4; c++) {
            float4 f0, f1;
            if (ga < N) { f0 = ax[c * 2]; f1 = ax[c * 2 + 1]; }
            else { f0 = make_float4(0.f, 0.f, 0.f, 0.f); f1 = f0; }
            float fs[8] = {f0.x, f0.y, f0.z, f0.w, f1.x, f1.y, f1.z, f1.w};
            unsigned short h[8], l[8];
            #pragma unroll
            for (int j = 0; j < 8; j++) {
                h[j] = f2bf(fs[j]);
                l[j] = f2bf(fs[j] - bf2f(h[j]));
            }
            uint4 ph, pl;
            ph.x = (unsigned)h[0] | ((unsigned)h[1] << 16);
            ph.y = (unsigned)h[2] | ((unsigned)h[3] << 16);
            ph.z = (unsigned)h[4] | ((unsigned)h[5] << 16);
            ph.w = (unsigned)h[6] | ((unsigned)h[7] << 16);
            pl.x = (unsigned)l[0] | ((unsigned)l[1] << 16);
            pl.y = (unsigned)l[2] | ((unsigned)l[3] << 16);
            pl.z = (unsigned)l[4] | ((unsigned)l[5] << 16);
            pl.w = (unsigned)l[6] | ((unsigned)l[7] << 16);
            int k8 = half * 4 + c;
            int sw = row * 8 + (k8 ^ (row & 7));
            Ah[sw] = ph; Al[sw] = pl;
        }
        const uint4* bwh = (const uint4*)(Wbf + (size_t)(1024 + gb) * 512 + kt + half * 32);
        const uint4* bwl = (const uint4*)(Wlo + (size_t)gb * 512 + kt + half * 32);
        #pragma unroll
        for (int c = 0; c < 4; c++) {
            int k8 = half * 4 + c;
            int sw = row * 8 + (k8 ^ (row & 7));
            Bh[sw] = bwh[c];
            Bl[sw] = bwl[c];
        }
        __syncthreads();
        #pragma unroll
        for (int kk = 0; kk < 2; kk++) {
            bf16x8 ah[4], al[4], bh[4], bl[4];
            #pragma unroll
            for (int ni = 0; ni < 4; ni++) {
                int ar = wr * 64 + ni * 16 + (lane & 15);
                int k8 = kk * 4 + (lane >> 4);
                int sw = ar * 8 + (k8 ^ (ar & 7));
                ah[ni] = __builtin_bit_cast(bf16x8, Ah[sw]);
                al[ni] = __builtin_bit_cast(bf16x8, Al[sw]);
            }
            #pragma unroll
            for (int mi = 0; mi < 4; mi++) {
                int br = wc * 64 + mi * 16 + (lane & 15);
                int k8 = kk * 4 + (lane >> 4);
                int sw = br * 8 + (k8 ^ (br & 7));
                bh[mi] = __builtin_bit_cast(bf16x8, Bh[sw]);
                bl[mi] = __builtin_bit_cast(bf16x8, Bl[sw]);
            }
            #pragma unroll
            for (int mi = 0; mi < 4; mi++)
                #pragma unroll
                for (int ni = 0; ni < 4; ni++) {
                    acc[mi][ni] = __builtin_amdgcn_mfma_f32_16x16x32_bf16(
                        ah[ni], bh[mi], acc[mi][ni], 0, 0, 0);
                    acc[mi][ni] = __builtin_amdgcn_mfma_f32_16x16x32_bf16(
                        al[ni], bh[mi], acc[mi][ni], 0, 0, 0);
                    acc[mi][ni] = __builtin_amdgcn_mfma_f32_16x16x32_bf16(
                        ah[ni], bl[mi], acc[mi][ni], 0, 0, 0);
                }
        }
        __syncthreads();
    }

    const int nbase = bm * 128 + wr * 64 + (lane >> 4) * 4;
    const int mbase = bn * 128 + wc * 64 + (lane & 15);
    #pragma unroll
    for (int mi = 0; mi < 4; mi++) {
        int m = mbase + mi * 16;
        #pragma unroll
        for (int ni = 0; ni < 4; ni++) {
            int n0 = nbase + ni * 16;
            #pragma unroll
            for (int j = 0; j < 4; j++)
                Yc[(size_t)(n0 + j) * 512 + m] = acc[mi][ni][j];
        }
    }
}

// ---------------- out init: bias + self-loop bond term
__global__ __launch_bounds__(256) void k_init_out(
    const unsigned short* __restrict__ Ybv, const float* __restrict__ dinv,
    const float* __restrict__ bias, float* __restrict__ out, int N)
{
    int tid = blockIdx.x * 256 + threadIdx.x;
    int n = tid >> 6, l = tid & 63;
    if (n >= N) return;
    float d2 = dinv[n] * dinv[n];
    uint4 v = *((const uint4*)(Ybv + (size_t)n * 1024) + l);
    const float4* bp = (const float4*)(bias + l * 8);
    float4 b0 = bp[0], b1 = bp[1];
    float4 o0, o1;
    o0.x = b0.x + d2 * bf2f((unsigned short)(v.x & 0xffff));
    o0.y = b0.y + d2 * bf2f((unsigned short)(v.x >> 16));
    o0.z = b0.z + d2 * bf2f((unsigned short)(v.y & 0xffff));
    o0.w = b0.w + d2 * bf2f((unsigned short)(v.y >> 16));
    o1.x = b1.x + d2 * bf2f((unsigned short)(v.z & 0xffff));
    o1.y = b1.y + d2 * bf2f((unsigned short)(v.z >> 16));
    o1.z = b1.z + d2 * bf2f((unsigned short)(v.w & 0xffff));
    o1.w = b1.w + d2 * bf2f((unsigned short)(v.w >> 16));
    float4* dst = (float4*)(out + (size_t)n * 512 + l * 8);
    dst[0] = o0; dst[1] = o1;
}

// ---------------- bond edges: out[r] += dinv[r]*dinv[c] * Ybond[c]
__global__ __launch_bounds__(256) void k_bond(
    const int* __restrict__ eb, int E, const unsigned short* __restrict__ Ybv,
    const float* __restrict__ dinv, float* __restrict__ out)
{
    int e = blockIdx.x * 4 + (threadIdx.x >> 6);
    if (e >= E) return;
    int lane = threadIdx.x & 63;
    int r = eb[e], c = eb[E + e];
    float norm = dinv[r] * dinv[c];
    uint4 v = *((const uint4*)(Ybv + (size_t)c * 1024) + lane);
    float* dst = out + (size_t)r * 512 + lane * 8;
    unsafeAtomicAdd(dst + 0, norm * bf2f((unsigned short)(v.x & 0xffff)));
    unsafeAtomicAdd(dst + 1, norm * bf2f((unsigned short)(v.x >> 16)));
    unsafeAtomicAdd(dst + 2, norm * bf2f((unsigned short)(v.y & 0xffff)));
    unsafeAtomicAdd(dst + 3, norm * bf2f((unsigned short)(v.y >> 16)));
    unsafeAtomicAdd(dst + 4, norm * bf2f((unsigned short)(v.z & 0xffff)));
    unsafeAtomicAdd(dst + 5, norm * bf2f((unsigned short)(v.z >> 16)));
    unsafeAtomicAdd(dst + 6, norm * bf2f((unsigned short)(v.w & 0xffff)));
    unsafeAtomicAdd(dst + 7, norm * bf2f((unsigned short)(v.w >> 16)));
}

// ---------------- virtual intra edges: out[r] += Yvin[c] / degclip[r]
__global__ __launch_bounds__(256) void k_vin(
    const int* __restrict__ ev, int E, const unsigned short* __restrict__ Ybv,
    const float* __restrict__ vs, float* __restrict__ out)
{
    int e = blockIdx.x * 4 + (threadIdx.x >> 6);
    if (e >= E) return;
    int lane = threadIdx.x & 63;
    int r = ev[e], c = ev[E + e];
    float sc = vs[r];
    uint4 v = *((const uint4*)(Ybv + (size_t)c * 1024 + 512) + lane);
    float* dst = out + (size_t)r * 512 + lane * 8;
    unsafeAtomicAdd(dst + 0, sc * bf2f((unsigned short)(v.x & 0xffff)));
    unsafeAtomicAdd(dst + 1, sc * bf2f((unsigned short)(v.x >> 16)));
    unsafeAtomicAdd(dst + 2, sc * bf2f((unsigned short)(v.y & 0xffff)));
    unsafeAtomicAdd(dst + 3, sc * bf2f((unsigned short)(v.y >> 16)));
    unsafeAtomicAdd(dst + 4, sc * bf2f((unsigned short)(v.z & 0xffff)));
    unsafeAtomicAdd(dst + 5, sc * bf2f((unsigned short)(v.z >> 16)));
    unsafeAtomicAdd(dst + 6, sc * bf2f((unsigned short)(v.w & 0xffff)));
    unsafeAtomicAdd(dst + 7, sc * bf2f((unsigned short)(v.w >> 16)));
}

// ---------------- virtual conn edges: sigmoid dot attention
__global__ __launch_bounds__(256) void k_conn(
    const int* __restrict__ ec, int E, const float* __restrict__ Yc,
    const float* __restrict__ att, float* __restrict__ out)
{
    int e = blockIdx.x * 4 + (threadIdx.x >> 6);
    if (e >= E) return;
    int lane = threadIdx.x & 63;
    int r = ec[e], c = ec[E + e];
    const float4* pr = (const float4*)(Yc + (size_t)r * 512) + lane * 2;
    const float4* pc = (const float4*)(Yc + (size_t)c * 512) + lane * 2;
    const float4* pa = (const float4*)att + lane * 2;
    float4 r0 = pr[0], r1 = pr[1];
    float4 c0 = pc[0], c1 = pc[1];
    float4 a0 = pa[0], a1 = pa[1];
    float dot = r0.x * c0.x * (a0.x * a0.x) + r0.y * c0.y * (a0.y * a0.y)
              + r0.z * c0.z * (a0.z * a0.z) + r0.w * c0.w * (a0.w * a0.w)
              + r1.x * c1.x * (a1.x * a1.x) + r1.y * c1.y * (a1.y * a1.y)
              + r1.z * c1.z * (a1.z * a1.z) + r1.w * c1.w * (a1.w * a1.w);
    #pragma unroll
    for (int off = 32; off > 0; off >>= 1) dot += __shfl_xor(dot, off);
    float alpha = 1.0f / (1.0f + expf(-dot));
    float* dst = out + (size_t)r * 512 + lane * 8;
    unsafeAtomicAdd(dst + 0, alpha * c0.x);
    unsafeAtomicAdd(dst + 1, alpha * c0.y);
    unsafeAtomicAdd(dst + 2, alpha * c0.z);
    unsafeAtomicAdd(dst + 3, alpha * c0.w);
    unsafeAtomicAdd(dst + 4, alpha * c1.x);
    unsafeAtomicAdd(dst + 5, alpha * c1.y);
    unsafeAtomicAdd(dst + 6, alpha * c1.z);
    unsafeAtomicAdd(dst + 7, alpha * c1.w);
}

extern "C" void kernel_launch(void* const* d_in, const int* in_sizes, int n_in,
                              void* d_out, int out_size, void* d_ws, size_t ws_size,
                              hipStream_t stream) {
    const float* x    = (const float*)d_in[0];
    const int*   eb   = (const int*)d_in[1];
    const int*   ev   = (const int*)d_in[2];
    const int*   ec   = (const int*)d_in[3];
    const float* Wb   = (const float*)d_in[4];
    const float* Wv   = (const float*)d_in[5];
    const float* Wc   = (const float*)d_in[6];
    const float* att  = (const float*)d_in[7];
    const float* bias = (const float*)d_in[8];
    float* out = (float*)d_out;

    const int N  = in_sizes[0] / 512;
    const int Eb = in_sizes[1] / 2;
    const int Ev = in_sizes[2] / 2;
    const int Ec = in_sizes[3] / 2;
    const int nbm = (N + 127) / 128;
    const size_t Npad = (size_t)nbm * 128;

    char* p = (char*)d_ws;
    unsigned short* Ybv = (unsigned short*)p; p += Npad * 1024 * 2;  // bond|vin bf16
    float*          Yc  = (float*)p;          p += Npad * 512 * 4;   // vconn f32
    unsigned short* Wbf = (unsigned short*)p; p += (size_t)1536 * 512 * 2;
    unsigned short* Wlo = (unsigned short*)p; p += (size_t)512 * 512 * 2;
    float* degb = (float*)p; p += ((size_t)N * 4 + 255) & ~(size_t)255;
    float* degv = (float*)p; p += ((size_t)N * 4 + 255) & ~(size_t)255;
    float* dinv = (float*)p; p += ((size_t)N * 4 + 255) & ~(size_t)255;
    float* vs   = (float*)p; p += ((size_t)N * 4 + 255) & ~(size_t)255;

    k_convert_w<<<(1536 * 512 + 255) / 256, 256, 0, stream>>>(Wb, Wv, Wc, Wbf, Wlo);
    k_init_deg<<<(N + 255) / 256, 256, 0, stream>>>(degb, degv, N);
    k_count<<<(Eb + 255) / 256, 256, 0, stream>>>(eb, Eb, degb);
    k_count<<<(Ev + 255) / 256, 256, 0, stream>>>(ev, Ev, degv);
    k_finish_deg<<<(N + 255) / 256, 256, 0, stream>>>(degb, degv, dinv, vs, N);
    k_gemm<<<dim3(nbm, 8), 256, 0, stream>>>(x, Wbf, Ybv, N);
    k_gemm_split<<<dim3(nbm, 4), 256, 0, stream>>>(x, Wbf, Wlo, Yc, N);
    k_init_out<<<(N * 64 + 255) / 256, 256, 0, stream>>>(Ybv, dinv, bias, out, N);
    k_bond<<<(Eb + 3) / 4, 256, 0, stream>>>(eb, Eb, Ybv, dinv, out);
    k_vin<<<(Ev + 3) / 4, 256, 0, stream>>>(ev, Ev, Ybv, vs, out);
    k_conn<<<(Ec + 3) / 4, 256, 0, stream>>>(ec, Ec, Yc, att, out);
}

// Round 3
// 765.202 us; speedup vs baseline: 21.8895x; 21.8895x over previous
//
#include <hip/hip_runtime.h>
#include <stdint.h>

typedef __bf16 bf16x8 __attribute__((ext_vector_type(8)));
typedef float f32x4 __attribute__((ext_vector_type(4)));

__device__ __forceinline__ unsigned short f2bf(float f) {
    union { float f; unsigned u; } v; v.f = f;
    unsigned u = v.u;
    unsigned r = u + 0x7fffu + ((u >> 16) & 1u);
    return (unsigned short)(r >> 16);
}
__device__ __forceinline__ float bf2f(unsigned short s) {
    union { unsigned u; float f; } v; v.u = ((unsigned)s) << 16; return v.f;
}

// ---------------- W conversion: stack [W_bond; W_vin; W_vconn] as bf16 [1536][512]
// plus lo-residual for W_vconn (split precision)
__global__ __launch_bounds__(256) void k_convert_w(
    const float* __restrict__ Wb, const float* __restrict__ Wv,
    const float* __restrict__ Wc, unsigned short* __restrict__ Wbf,
    unsigned short* __restrict__ Wlo)
{
    int idx = blockIdx.x * 256 + threadIdx.x;
    if (idx >= 1536 * 512) return;
    int m = idx >> 9, k = idx & 511;
    float s;
    if (m < 512)       s = Wb[m * 512 + k];
    else if (m < 1024) s = Wv[(m - 512) * 512 + k];
    else               s = Wc[(m - 1024) * 512 + k];
    unsigned short hi = f2bf(s);
    Wbf[idx] = hi;
    if (m >= 1024) Wlo[(size_t)(m - 1024) * 512 + k] = f2bf(s - bf2f(hi));
}

// ---------------- CSR build ----------------
// cnt/ptr/cur are over 3N virtual rows: bond [0,N), vin [N,2N), conn [2N,3N)
__global__ __launch_bounds__(256) void k_hist(
    const int* __restrict__ e, int E, int* __restrict__ cnt, int off)
{
    int i = blockIdx.x * 256 + threadIdx.x;
    if (i < E) atomicAdd(cnt + off + e[i], 1);
}

// scan A: per-block (1024 elems) exclusive scan, emit block sums
__global__ __launch_bounds__(256) void k_scan_a(
    const int* __restrict__ cnt, int* __restrict__ ptr, int* __restrict__ bsum, int M)
{
    __shared__ int sh[256];
    int t = threadIdx.x;
    int base = blockIdx.x * 1024 + t * 4;
    int v[4];
    #pragma unroll
    for (int j = 0; j < 4; j++) v[j] = (base + j < M) ? cnt[base + j] : 0;
    int local = v[0] + v[1] + v[2] + v[3];
    sh[t] = local; __syncthreads();
    #pragma unroll
    for (int off = 1; off < 256; off <<= 1) {
        int x = (t >= off) ? sh[t - off] : 0;
        __syncthreads();
        sh[t] += x;
        __syncthreads();
    }
    int run = sh[t] - local;   // exclusive prefix within block
    #pragma unroll
    for (int j = 0; j < 4; j++) {
        if (base + j < M) ptr[base + j] = run;
        run += v[j];
    }
    if (t == 255) bsum[blockIdx.x] = sh[255];
}

// scan B: single block scans block sums (nb <= 256)
__global__ __launch_bounds__(256) void k_scan_b(int* __restrict__ bsum, int nb)
{
    __shared__ int sh[256];
    int t = threadIdx.x;
    int v = (t < nb) ? bsum[t] : 0;
    sh[t] = v; __syncthreads();
    #pragma unroll
    for (int off = 1; off < 256; off <<= 1) {
        int x = (t >= off) ? sh[t - off] : 0;
        __syncthreads();
        sh[t] += x;
        __syncthreads();
    }
    if (t < nb) bsum[t] = sh[t] - v;  // exclusive
}

// scan C: add block offsets; also init cursor copy and tail sentinel
__global__ __launch_bounds__(256) void k_scan_c(
    int* __restrict__ ptr, const int* __restrict__ bsum, int* __restrict__ cur,
    int M, int total)
{
    int idx = blockIdx.x * 256 + threadIdx.x;
    if (idx < M) {
        int p = ptr[idx] + bsum[idx >> 10];
        ptr[idx] = p;
        cur[idx] = p;
    }
    if (idx == 0) ptr[M] = total;
}

__global__ __launch_bounds__(256) void k_dinv(
    const int* __restrict__ cnt, float* __restrict__ dinv, int N)
{
    int n = blockIdx.x * 256 + threadIdx.x;
    if (n < N) dinv[n] = rsqrtf((float)(cnt[n] + 1));  // +1 self loop
}

__global__ __launch_bounds__(256) void k_scatter(
    const int* __restrict__ e, int E, int* __restrict__ cur,
    int* __restrict__ cidx, int off)
{
    int i = blockIdx.x * 256 + threadIdx.x;
    if (i >= E) return;
    int r = e[i], c = e[E + i];
    int pos = atomicAdd(cur + off + r, 1);
    cidx[pos] = c;
}

// ---------------- GEMM (bond|vin): Y[n,m] = sum_k x[n,k] * Wst[m,k]
// 128x128 tile, BK=64, 4 waves (2x2), 16x16x32 bf16 MFMA, XOR-swizzled LDS.
__global__ __launch_bounds__(256) void k_gemm(
    const float* __restrict__ x, const unsigned short* __restrict__ Wbf,
    unsigned short* __restrict__ Ybv, int N)
{
    __shared__ uint4 As[1024];  // [row][k8swz]  row*8 + (k8 ^ (row&7))
    __shared__ uint4 Bs[1024];

    const int t = threadIdx.x;
    const int bm = blockIdx.x, bn = blockIdx.y;
    const int row = t >> 1, half = t & 1;
    const int ga = bm * 128 + row;   // x row
    const int gb = bn * 128 + row;   // stacked-W row (0..1023)
    const int lane = t & 63;
    const int w = t >> 6;
    const int wr = w >> 1, wc = w & 1;

    f32x4 acc[4][4];
    #pragma unroll
    for (int i = 0; i < 4; i++)
        #pragma unroll
        for (int j = 0; j < 4; j++) acc[i][j] = (f32x4){0.f, 0.f, 0.f, 0.f};

    for (int kt = 0; kt < 512; kt += 64) {
        const float4* ax = (const float4*)(x + (size_t)ga * 512 + kt + half * 32);
        #pragma unroll
        for (int c = 0; c < 4; c++) {
            float4 f0, f1;
            if (ga < N) { f0 = ax[c * 2]; f1 = ax[c * 2 + 1]; }
            else { f0 = make_float4(0.f, 0.f, 0.f, 0.f); f1 = f0; }
            uint4 p;
            p.x = (unsigned)f2bf(f0.x) | ((unsigned)f2bf(f0.y) << 16);
            p.y = (unsigned)f2bf(f0.z) | ((unsigned)f2bf(f0.w) << 16);
            p.z = (unsigned)f2bf(f1.x) | ((unsigned)f2bf(f1.y) << 16);
            p.w = (unsigned)f2bf(f1.z) | ((unsigned)f2bf(f1.w) << 16);
            int k8 = half * 4 + c;
            As[row * 8 + (k8 ^ (row & 7))] = p;
        }
        const uint4* bw = (const uint4*)(Wbf + (size_t)gb * 512 + kt + half * 32);
        #pragma unroll
        for (int c = 0; c < 4; c++) {
            uint4 p = bw[c];
            int k8 = half * 4 + c;
            Bs[row * 8 + (k8 ^ (row & 7))] = p;
        }
        __syncthreads();
        #pragma unroll
        for (int kk = 0; kk < 2; kk++) {
            bf16x8 a[4], b[4];
            #pragma unroll
            for (int ni = 0; ni < 4; ni++) {
                int ar = wr * 64 + ni * 16 + (lane & 15);
                int k8 = kk * 4 + (lane >> 4);
                a[ni] = __builtin_bit_cast(bf16x8, As[ar * 8 + (k8 ^ (ar & 7))]);
            }
            #pragma unroll
            for (int mi = 0; mi < 4; mi++) {
                int br = wc * 64 + mi * 16 + (lane & 15);
                int k8 = kk * 4 + (lane >> 4);
                b[mi] = __builtin_bit_cast(bf16x8, Bs[br * 8 + (k8 ^ (br & 7))]);
            }
            #pragma unroll
            for (int mi = 0; mi < 4; mi++)
                #pragma unroll
                for (int ni = 0; ni < 4; ni++)
                    acc[mi][ni] = __builtin_amdgcn_mfma_f32_16x16x32_bf16(
                        a[ni], b[mi], acc[mi][ni], 0, 0, 0);
        }
        __syncthreads();
    }

    const int nbase = bm * 128 + wr * 64 + (lane >> 4) * 4;
    const int mbase = bn * 128 + wc * 64 + (lane & 15);
    #pragma unroll
    for (int mi = 0; mi < 4; mi++) {
        int m = mbase + mi * 16;
        #pragma unroll
        for (int ni = 0; ni < 4; ni++) {
            int n0 = nbase + ni * 16;
            #pragma unroll
            for (int j = 0; j < 4; j++)
                Ybv[(size_t)(n0 + j) * 1024 + m] = f2bf(acc[mi][ni][j]);
        }
    }
}

// ---------------- GEMM (vconn, split-precision): Yc[n,m] f32
__global__ __launch_bounds__(256) void k_gemm_split(
    const float* __restrict__ x, const unsigned short* __restrict__ Wbf,
    const unsigned short* __restrict__ Wlo, float* __restrict__ Yc, int N)
{
    __shared__ uint4 Ah[1024], Al[1024], Bh[1024], Bl[1024];

    const int t = threadIdx.x;
    const int bm = blockIdx.x, bn = blockIdx.y;  // bn in [0,4)
    const int row = t >> 1, half = t & 1;
    const int ga = bm * 128 + row;
    const int gb = bn * 128 + row;               // 0..511 (vconn row)
    const int lane = t & 63;
    const int w = t >> 6;
    const int wr = w >> 1, wc = w & 1;

    f32x4 acc[4][4];
    #pragma unroll
    for (int i = 0; i < 4; i++)
        #pragma unroll
        for (int j = 0; j < 4; j++) acc[i][j] = (f32x4){0.f, 0.f, 0.f, 0.f};

    for (int kt = 0; kt < 512; kt += 64) {
        const float4* ax = (const float4*)(x + (size_t)ga * 512 + kt + half * 32);
        #pragma unroll
        for (int c = 0; c < 4; c++) {
            float4 f0, f1;
            if (ga < N) { f0 = ax[c * 2]; f1 = ax[c * 2 + 1]; }
            else { f0 = make_float4(0.f, 0.f, 0.f, 0.f); f1 = f0; }
            float fs[8] = {f0.x, f0.y, f0.z, f0.w, f1.x, f1.y, f1.z, f1.w};
            unsigned short h[8], l[8];
            #pragma unroll
            for (int j = 0; j < 8; j++) {
                h[j] = f2bf(fs[j]);
                l[j] = f2bf(fs[j] - bf2f(h[j]));
            }
            uint4 ph, pl;
            ph.x = (unsigned)h[0] | ((unsigned)h[1] << 16);
            ph.y = (unsigned)h[2] | ((unsigned)h[3] << 16);
            ph.z = (unsigned)h[4] | ((unsigned)h[5] << 16);
            ph.w = (unsigned)h[6] | ((unsigned)h[7] << 16);
            pl.x = (unsigned)l[0] | ((unsigned)l[1] << 16);
            pl.y = (unsigned)l[2] | ((unsigned)l[3] << 16);
            pl.z = (unsigned)l[4] | ((unsigned)l[5] << 16);
            pl.w = (unsigned)l[6] | ((unsigned)l[7] << 16);
            int k8 = half * 4 + c;
            int sw = row * 8 + (k8 ^ (row & 7));
            Ah[sw] = ph; Al[sw] = pl;
        }
        const uint4* bwh = (const uint4*)(Wbf + (size_t)(1024 + gb) * 512 + kt + half * 32);
        const uint4* bwl = (const uint4*)(Wlo + (size_t)gb * 512 + kt + half * 32);
        #pragma unroll
        for (int c = 0; c < 4; c++) {
            int k8 = half * 4 + c;
            int sw = row * 8 + (k8 ^ (row & 7));
            Bh[sw] = bwh[c];
            Bl[sw] = bwl[c];
        }
        __syncthreads();
        #pragma unroll
        for (int kk = 0; kk < 2; kk++) {
            bf16x8 ah[4], al[4], bh[4], bl[4];
            #pragma unroll
            for (int ni = 0; ni < 4; ni++) {
                int ar = wr * 64 + ni * 16 + (lane & 15);
                int k8 = kk * 4 + (lane >> 4);
                int sw = ar * 8 + (k8 ^ (ar & 7));
                ah[ni] = __builtin_bit_cast(bf16x8, Ah[sw]);
                al[ni] = __builtin_bit_cast(bf16x8, Al[sw]);
            }
            #pragma unroll
            for (int mi = 0; mi < 4; mi++) {
                int br = wc * 64 + mi * 16 + (lane & 15);
                int k8 = kk * 4 + (lane >> 4);
                int sw = br * 8 + (k8 ^ (br & 7));
                bh[mi] = __builtin_bit_cast(bf16x8, Bh[sw]);
                bl[mi] = __builtin_bit_cast(bf16x8, Bl[sw]);
            }
            #pragma unroll
            for (int mi = 0; mi < 4; mi++)
                #pragma unroll
                for (int ni = 0; ni < 4; ni++) {
                    acc[mi][ni] = __builtin_amdgcn_mfma_f32_16x16x32_bf16(
                        ah[ni], bh[mi], acc[mi][ni], 0, 0, 0);
                    acc[mi][ni] = __builtin_amdgcn_mfma_f32_16x16x32_bf16(
                        al[ni], bh[mi], acc[mi][ni], 0, 0, 0);
                    acc[mi][ni] = __builtin_amdgcn_mfma_f32_16x16x32_bf16(
                        ah[ni], bl[mi], acc[mi][ni], 0, 0, 0);
                }
        }
        __syncthreads();
    }

    const int nbase = bm * 128 + wr * 64 + (lane >> 4) * 4;
    const int mbase = bn * 128 + wc * 64 + (lane & 15);
    #pragma unroll
    for (int mi = 0; mi < 4; mi++) {
        int m = mbase + mi * 16;
        #pragma unroll
        for (int ni = 0; ni < 4; ni++) {
            int n0 = nbase + ni * 16;
            #pragma unroll
            for (int j = 0; j < 4; j++)
                Yc[(size_t)(n0 + j) * 512 + m] = acc[mi][ni][j];
        }
    }
}

// ---------------- fused gather: one wave per node
// out[r] = bias + dinv[r]^2*Yb[r] + sum_bond dinv[r]dinv[c]*Yb[c]
//        + (1/max(degv,1)) * sum_vin Yv[c] + sum_conn sigmoid(P[r].Yc[c])*Yc[c]
__global__ __launch_bounds__(256) void k_gather(
    const int* __restrict__ ptr, const int* __restrict__ cidx,
    const float* __restrict__ dinv,
    const unsigned short* __restrict__ Ybv, const float* __restrict__ Yc,
    const float* __restrict__ att, const float* __restrict__ bias,
    float* __restrict__ out, int N)
{
    int node = blockIdx.x * 4 + (threadIdx.x >> 6);
    if (node >= N) return;
    int lane = threadIdx.x & 63;

    float a[8];
    {
        const float4* bp = (const float4*)(bias + lane * 8);
        float4 q0 = bp[0], q1 = bp[1];
        a[0] = q0.x; a[1] = q0.y; a[2] = q0.z; a[3] = q0.w;
        a[4] = q1.x; a[5] = q1.y; a[6] = q1.z; a[7] = q1.w;
    }

    float di = dinv[node];
    // self loop (bond)
    {
        uint4 v = *((const uint4*)(Ybv + (size_t)node * 1024) + lane);
        float d2 = di * di;
        a[0] += d2 * bf2f((unsigned short)(v.x & 0xffff));
        a[1] += d2 * bf2f((unsigned short)(v.x >> 16));
        a[2] += d2 * bf2f((unsigned short)(v.y & 0xffff));
        a[3] += d2 * bf2f((unsigned short)(v.y >> 16));
        a[4] += d2 * bf2f((unsigned short)(v.z & 0xffff));
        a[5] += d2 * bf2f((unsigned short)(v.z >> 16));
        a[6] += d2 * bf2f((unsigned short)(v.w & 0xffff));
        a[7] += d2 * bf2f((unsigned short)(v.w >> 16));
    }
    // bond edges
    {
        int e0 = ptr[node], e1 = ptr[node + 1];
        for (int e = e0; e < e1; ++e) {
            int c = cidx[e];
            float nrm = di * dinv[c];
            uint4 v = *((const uint4*)(Ybv + (size_t)c * 1024) + lane);
            a[0] += nrm * bf2f((unsigned short)(v.x & 0xffff));
            a[1] += nrm * bf2f((unsigned short)(v.x >> 16));
            a[2] += nrm * bf2f((unsigned short)(v.y & 0xffff));
            a[3] += nrm * bf2f((unsigned short)(v.y >> 16));
            a[4] += nrm * bf2f((unsigned short)(v.z & 0xffff));
            a[5] += nrm * bf2f((unsigned short)(v.z >> 16));
            a[6] += nrm * bf2f((unsigned short)(v.w & 0xffff));
            a[7] += nrm * bf2f((unsigned short)(v.w >> 16));
        }
    }
    // vin edges (mean)
    {
        int e0 = ptr[N + node], e1 = ptr[N + node + 1];
        float vsc = 1.0f / (float)((e1 - e0) > 1 ? (e1 - e0) : 1);
        for (int e = e0; e < e1; ++e) {
            int c = cidx[e];
            uint4 v = *((const uint4*)(Ybv + (size_t)c * 1024 + 512) + lane);
            a[0] += vsc * bf2f((unsigned short)(v.x & 0xffff));
            a[1] += vsc * bf2f((unsigned short)(v.x >> 16));
            a[2] += vsc * bf2f((unsigned short)(v.y & 0xffff));
            a[3] += vsc * bf2f((unsigned short)(v.y >> 16));
            a[4] += vsc * bf2f((unsigned short)(v.z & 0xffff));
            a[5] += vsc * bf2f((unsigned short)(v.z >> 16));
            a[6] += vsc * bf2f((unsigned short)(v.w & 0xffff));
            a[7] += vsc * bf2f((unsigned short)(v.w >> 16));
        }
    }
    // conn edges (sigmoid dot attention)
    {
        int e0 = ptr[2 * N + node], e1 = ptr[2 * N + node + 1];
        if (e0 < e1) {
            const float4* ap = (const float4*)att + lane * 2;
            float4 t0 = ap[0], t1 = ap[1];
            const float4* yr = (const float4*)(Yc + (size_t)node * 512) + lane * 2;
            float4 r0 = yr[0], r1 = yr[1];
            float p[8];
            p[0] = r0.x * t0.x * t0.x; p[1] = r0.y * t0.y * t0.y;
            p[2] = r0.z * t0.z * t0.z; p[3] = r0.w * t0.w * t0.w;
            p[4] = r1.x * t1.x * t1.x; p[5] = r1.y * t1.y * t1.y;
            p[6] = r1.z * t1.z * t1.z; p[7] = r1.w * t1.w * t1.w;
            for (int e = e0; e < e1; ++e) {
                int c = cidx[e];
                const float4* yp = (const float4*)(Yc + (size_t)c * 512) + lane * 2;
                float4 c0 = yp[0], c1 = yp[1];
                float dot = p[0] * c0.x + p[1] * c0.y + p[2] * c0.z + p[3] * c0.w
                          + p[4] * c1.x + p[5] * c1.y + p[6] * c1.z + p[7] * c1.w;
                #pragma unroll
                for (int off = 32; off > 0; off >>= 1) dot += __shfl_xor(dot, off);
                float alpha = 1.0f / (1.0f + expf(-dot));
                a[0] += alpha * c0.x; a[1] += alpha * c0.y;
                a[2] += alpha * c0.z; a[3] += alpha * c0.w;
                a[4] += alpha * c1.x; a[5] += alpha * c1.y;
                a[6] += alpha * c1.z; a[7] += alpha * c1.w;
            }
        }
    }
    float4 o0 = make_float4(a[0], a[1], a[2], a[3]);
    float4 o1 = make_float4(a[4], a[5], a[6], a[7]);
    float4* dst = (float4*)(out + (size_t)node * 512 + lane * 8);
    dst[0] = o0; dst[1] = o1;
}

extern "C" void kernel_launch(void* const* d_in, const int* in_sizes, int n_in,
                              void* d_out, int out_size, void* d_ws, size_t ws_size,
                              hipStream_t stream) {
    const float* x    = (const float*)d_in[0];
    const int*   eb   = (const int*)d_in[1];
    const int*   ev   = (const int*)d_in[2];
    const int*   ec   = (const int*)d_in[3];
    const float* Wb   = (const float*)d_in[4];
    const float* Wv   = (const float*)d_in[5];
    const float* Wc   = (const float*)d_in[6];
    const float* att  = (const float*)d_in[7];
    const float* bias = (const float*)d_in[8];
    float* out = (float*)d_out;

    const int N  = in_sizes[0] / 512;
    const int Eb = in_sizes[1] / 2;
    const int Ev = in_sizes[2] / 2;
    const int Ec = in_sizes[3] / 2;
    const int Etot = Eb + Ev + Ec;
    const int nbm = (N + 127) / 128;
    const size_t Npad = (size_t)nbm * 128;
    const int M = 3 * N;                 // virtual CSR rows
    const int nScanBlocks = (M + 1023) / 1024;

    char* p = (char*)d_ws;
    unsigned short* Ybv = (unsigned short*)p; p += Npad * 1024 * 2;  // bond|vin bf16
    float*          Yc  = (float*)p;          p += Npad * 512 * 4;   // vconn f32
    unsigned short* Wbf = (unsigned short*)p; p += (size_t)1536 * 512 * 2;
    unsigned short* Wlo = (unsigned short*)p; p += (size_t)512 * 512 * 2;
    int* cnt  = (int*)p; p += ((size_t)M * 4 + 255) & ~(size_t)255;
    int* ptr_ = (int*)p; p += ((size_t)(M + 1) * 4 + 255) & ~(size_t)255;
    int* cur  = (int*)p; p += ((size_t)M * 4 + 255) & ~(size_t)255;
    int* bsum = (int*)p; p += 256 * 4;
    int* cidx = (int*)p; p += ((size_t)Etot * 4 + 255) & ~(size_t)255;
    float* dinv = (float*)p; p += ((size_t)N * 4 + 255) & ~(size_t)255;

    // --- CSR build ---
    hipMemsetAsync(cnt, 0, (size_t)M * 4, stream);
    k_hist<<<(Eb + 255) / 256, 256, 0, stream>>>(eb, Eb, cnt, 0);
    k_hist<<<(Ev + 255) / 256, 256, 0, stream>>>(ev, Ev, cnt, N);
    k_hist<<<(Ec + 255) / 256, 256, 0, stream>>>(ec, Ec, cnt, 2 * N);
    k_scan_a<<<nScanBlocks, 256, 0, stream>>>(cnt, ptr_, bsum, M);
    k_scan_b<<<1, 256, 0, stream>>>(bsum, nScanBlocks);
    k_scan_c<<<(M + 255) / 256, 256, 0, stream>>>(ptr_, bsum, cur, M, Etot);
    k_dinv<<<(N + 255) / 256, 256, 0, stream>>>(cnt, dinv, N);
    k_scatter<<<(Eb + 255) / 256, 256, 0, stream>>>(eb, Eb, cur, cidx, 0);
    k_scatter<<<(Ev + 255) / 256, 256, 0, stream>>>(ev, Ev, cur, cidx, N);
    k_scatter<<<(Ec + 255) / 256, 256, 0, stream>>>(ec, Ec, cur, cidx, 2 * N);

    // --- GEMMs ---
    k_convert_w<<<(1536 * 512 + 255) / 256, 256, 0, stream>>>(Wb, Wv, Wc, Wbf, Wlo);
    k_gemm<<<dim3(nbm, 8), 256, 0, stream>>>(x, Wbf, Ybv, N);
    k_gemm_split<<<dim3(nbm, 4), 256, 0, stream>>>(x, Wbf, Wlo, Yc, N);

    // --- fused gather ---
    k_gather<<<(N + 3) / 4, 256, 0, stream>>>(ptr_, cidx, dinv, Ybv, Yc, att, bias, out, N);
}

// Round 4
// 632.929 us; speedup vs baseline: 26.4641x; 1.2090x over previous
//
#include <hip/hip_runtime.h>
#include <stdint.h>

typedef __bf16 bf16x8 __attribute__((ext_vector_type(8)));
typedef float f32x4 __attribute__((ext_vector_type(4)));

__device__ __forceinline__ unsigned short f2bf(float f) {
    union { float f; unsigned u; } v; v.f = f;
    unsigned u = v.u;
    unsigned r = u + 0x7fffu + ((u >> 16) & 1u);
    return (unsigned short)(r >> 16);
}
__device__ __forceinline__ float bf2f(unsigned short s) {
    union { unsigned u; float f; } v; v.u = ((unsigned)s) << 16; return v.f;
}

__device__ __forceinline__ void gload16(const void* g, void* lds) {
    __builtin_amdgcn_global_load_lds(
        (const __attribute__((address_space(1))) void*)g,
        (__attribute__((address_space(3))) void*)lds, 16, 0, 0);
}

// ---------------- W conversion: stack [W_bond; W_vin; W_vconn] as bf16 [1536][512]
// plus lo-residual for W_vconn (split precision)
__global__ __launch_bounds__(256) void k_convert_w(
    const float* __restrict__ Wb, const float* __restrict__ Wv,
    const float* __restrict__ Wc, unsigned short* __restrict__ Wbf,
    unsigned short* __restrict__ Wlo)
{
    int idx = blockIdx.x * 256 + threadIdx.x;
    if (idx >= 1536 * 512) return;
    int m = idx >> 9, k = idx & 511;
    float s;
    if (m < 512)       s = Wb[m * 512 + k];
    else if (m < 1024) s = Wv[(m - 512) * 512 + k];
    else               s = Wc[(m - 1024) * 512 + k];
    unsigned short hi = f2bf(s);
    Wbf[idx] = hi;
    if (m >= 1024) Wlo[(size_t)(m - 1024) * 512 + k] = f2bf(s - bf2f(hi));
}

// ---------------- x split: f32 -> bf16 hi + bf16 lo, zero-padded to Npad rows
__global__ __launch_bounds__(256) void k_split_x(
    const float* __restrict__ x, unsigned short* __restrict__ xh,
    unsigned short* __restrict__ xl, size_t valid, size_t total)
{
    size_t idx = ((size_t)blockIdx.x * 256 + threadIdx.x) * 4;
    if (idx >= total) return;
    ushort4 h, l;
    if (idx < valid) {
        float4 f = *(const float4*)(x + idx);
        h.x = f2bf(f.x); l.x = f2bf(f.x - bf2f(h.x));
        h.y = f2bf(f.y); l.y = f2bf(f.y - bf2f(h.y));
        h.z = f2bf(f.z); l.z = f2bf(f.z - bf2f(h.z));
        h.w = f2bf(f.w); l.w = f2bf(f.w - bf2f(h.w));
    } else {
        h.x = h.y = h.z = h.w = 0;
        l = h;
    }
    *(ushort4*)(xh + idx) = h;
    *(ushort4*)(xl + idx) = l;
}

// ---------------- CSR build ----------------
__global__ __launch_bounds__(256) void k_hist(
    const int* __restrict__ e, int E, int* __restrict__ cnt, int off)
{
    int i = blockIdx.x * 256 + threadIdx.x;
    if (i < E) atomicAdd(cnt + off + e[i], 1);
}

__global__ __launch_bounds__(256) void k_scan_a(
    const int* __restrict__ cnt, int* __restrict__ ptr, int* __restrict__ bsum, int M)
{
    __shared__ int sh[256];
    int t = threadIdx.x;
    int base = blockIdx.x * 1024 + t * 4;
    int v[4];
    #pragma unroll
    for (int j = 0; j < 4; j++) v[j] = (base + j < M) ? cnt[base + j] : 0;
    int local = v[0] + v[1] + v[2] + v[3];
    sh[t] = local; __syncthreads();
    #pragma unroll
    for (int off = 1; off < 256; off <<= 1) {
        int x = (t >= off) ? sh[t - off] : 0;
        __syncthreads();
        sh[t] += x;
        __syncthreads();
    }
    int run = sh[t] - local;
    #pragma unroll
    for (int j = 0; j < 4; j++) {
        if (base + j < M) ptr[base + j] = run;
        run += v[j];
    }
    if (t == 255) bsum[blockIdx.x] = sh[255];
}

__global__ __launch_bounds__(256) void k_scan_b(int* __restrict__ bsum, int nb)
{
    __shared__ int sh[256];
    int t = threadIdx.x;
    int v = (t < nb) ? bsum[t] : 0;
    sh[t] = v; __syncthreads();
    #pragma unroll
    for (int off = 1; off < 256; off <<= 1) {
        int x = (t >= off) ? sh[t - off] : 0;
        __syncthreads();
        sh[t] += x;
        __syncthreads();
    }
    if (t < nb) bsum[t] = sh[t] - v;
}

__global__ __launch_bounds__(256) void k_scan_c(
    int* __restrict__ ptr, const int* __restrict__ bsum, int* __restrict__ cur,
    int M, int total)
{
    int idx = blockIdx.x * 256 + threadIdx.x;
    if (idx < M) {
        int p = ptr[idx] + bsum[idx >> 10];
        ptr[idx] = p;
        cur[idx] = p;
    }
    if (idx == 0) ptr[M] = total;
}

__global__ __launch_bounds__(256) void k_dinv(
    const int* __restrict__ cnt, float* __restrict__ dinv, int N)
{
    int n = blockIdx.x * 256 + threadIdx.x;
    if (n < N) dinv[n] = rsqrtf((float)(cnt[n] + 1));
}

__global__ __launch_bounds__(256) void k_scatter(
    const int* __restrict__ e, int E, int* __restrict__ cur,
    int* __restrict__ cidx, int off)
{
    int i = blockIdx.x * 256 + threadIdx.x;
    if (i >= E) return;
    int r = e[i], c = e[E + i];
    int pos = atomicAdd(cur + off + r, 1);
    cidx[pos] = c;
}

// ---------------- FAST GEMM (bond|vin): bf16 A via global_load_lds
// LDS slot r*8 + (k8 ^ (r&7)) holds logical chunk k8 of row r; staged with
// linear LDS dest + pre-swizzled global source (involution).
__global__ __launch_bounds__(256) void k_gemm_f(
    const unsigned short* __restrict__ xh, const unsigned short* __restrict__ Wbf,
    unsigned short* __restrict__ Ybv, int N)
{
    __shared__ uint4 As[1024];
    __shared__ uint4 Bs[1024];

    const int t = threadIdx.x;
    const int lane = t & 63;
    const int w = t >> 6;
    const int wr = w >> 1, wc = w & 1;
    const int bm = blockIdx.x, bn = blockIdx.y;
    const int rA = lane >> 3;     // row within 8-row segment
    const int cs = lane & 7;      // LDS chunk slot

    f32x4 acc[4][4];
    #pragma unroll
    for (int i = 0; i < 4; i++)
        #pragma unroll
        for (int j = 0; j < 4; j++) acc[i][j] = (f32x4){0.f, 0.f, 0.f, 0.f};

    const size_t baseA = (size_t)bm * 128 * 512;
    const size_t baseB = (size_t)bn * 128 * 512;

    for (int kt = 0; kt < 512; kt += 64) {
        #pragma unroll
        for (int j = 0; j < 4; j++) {
            int seg = w * 4 + j;
            int r = seg * 8 + rA;
            int cg = cs ^ (r & 7);
            gload16(xh + baseA + (size_t)r * 512 + kt + cg * 8, &As[seg * 64]);
            gload16(Wbf + baseB + (size_t)r * 512 + kt + cg * 8, &Bs[seg * 64]);
        }
        __syncthreads();
        #pragma unroll
        for (int kk = 0; kk < 2; kk++) {
            bf16x8 a[4], b[4];
            #pragma unroll
            for (int ni = 0; ni < 4; ni++) {
                int ar = wr * 64 + ni * 16 + (lane & 15);
                int k8 = kk * 4 + (lane >> 4);
                a[ni] = __builtin_bit_cast(bf16x8, As[ar * 8 + (k8 ^ (ar & 7))]);
            }
            #pragma unroll
            for (int mi = 0; mi < 4; mi++) {
                int br = wc * 64 + mi * 16 + (lane & 15);
                int k8 = kk * 4 + (lane >> 4);
                b[mi] = __builtin_bit_cast(bf16x8, Bs[br * 8 + (k8 ^ (br & 7))]);
            }
            #pragma unroll
            for (int mi = 0; mi < 4; mi++)
                #pragma unroll
                for (int ni = 0; ni < 4; ni++)
                    acc[mi][ni] = __builtin_amdgcn_mfma_f32_16x16x32_bf16(
                        a[ni], b[mi], acc[mi][ni], 0, 0, 0);
        }
        __syncthreads();
    }

    const int nbase = bm * 128 + wr * 64 + (lane >> 4) * 4;
    const int mbase = bn * 128 + wc * 64 + (lane & 15);
    #pragma unroll
    for (int mi = 0; mi < 4; mi++) {
        int m = mbase + mi * 16;
        #pragma unroll
        for (int ni = 0; ni < 4; ni++) {
            int n0 = nbase + ni * 16;
            #pragma unroll
            for (int j = 0; j < 4; j++)
                Ybv[(size_t)(n0 + j) * 1024 + m] = f2bf(acc[mi][ni][j]);
        }
    }
}

// ---------------- FAST GEMM (vconn, split-precision)
__global__ __launch_bounds__(256) void k_gemm_split_f(
    const unsigned short* __restrict__ xh, const unsigned short* __restrict__ xl,
    const unsigned short* __restrict__ Wbf, const unsigned short* __restrict__ Wlo,
    float* __restrict__ Yc, int N)
{
    __shared__ uint4 Ah[1024], Al[1024], Bh[1024], Bl[1024];

    const int t = threadIdx.x;
    const int lane = t & 63;
    const int w = t >> 6;
    const int wr = w >> 1, wc = w & 1;
    const int bm = blockIdx.x, bn = blockIdx.y;  // bn in [0,4)
    const int rA = lane >> 3;
    const int cs = lane & 7;

    f32x4 acc[4][4];
    #pragma unroll
    for (int i = 0; i < 4; i++)
        #pragma unroll
        for (int j = 0; j < 4; j++) acc[i][j] = (f32x4){0.f, 0.f, 0.f, 0.f};

    const size_t baseA = (size_t)bm * 128 * 512;
    const size_t baseBh = (size_t)(1024 + bn * 128) * 512;
    const size_t baseBl = (size_t)(bn * 128) * 512;

    for (int kt = 0; kt < 512; kt += 64) {
        #pragma unroll
        for (int j = 0; j < 4; j++) {
            int seg = w * 4 + j;
            int r = seg * 8 + rA;
            int cg = cs ^ (r & 7);
            size_t rowoff = (size_t)r * 512 + kt + cg * 8;
            gload16(xh + baseA + rowoff, &Ah[seg * 64]);
            gload16(xl + baseA + rowoff, &Al[seg * 64]);
            gload16(Wbf + baseBh + rowoff, &Bh[seg * 64]);
            gload16(Wlo + baseBl + rowoff, &Bl[seg * 64]);
        }
        __syncthreads();
        #pragma unroll
        for (int kk = 0; kk < 2; kk++) {
            bf16x8 ah[4], al[4], bh[4], bl[4];
            #pragma unroll
            for (int ni = 0; ni < 4; ni++) {
                int ar = wr * 64 + ni * 16 + (lane & 15);
                int k8 = kk * 4 + (lane >> 4);
                int sw = ar * 8 + (k8 ^ (ar & 7));
                ah[ni] = __builtin_bit_cast(bf16x8, Ah[sw]);
                al[ni] = __builtin_bit_cast(bf16x8, Al[sw]);
            }
            #pragma unroll
            for (int mi = 0; mi < 4; mi++) {
                int br = wc * 64 + mi * 16 + (lane & 15);
                int k8 = kk * 4 + (lane >> 4);
                int sw = br * 8 + (k8 ^ (br & 7));
                bh[mi] = __builtin_bit_cast(bf16x8, Bh[sw]);
                bl[mi] = __builtin_bit_cast(bf16x8, Bl[sw]);
            }
            #pragma unroll
            for (int mi = 0; mi < 4; mi++)
                #pragma unroll
                for (int ni = 0; ni < 4; ni++) {
                    acc[mi][ni] = __builtin_amdgcn_mfma_f32_16x16x32_bf16(
                        ah[ni], bh[mi], acc[mi][ni], 0, 0, 0);
                    acc[mi][ni] = __builtin_amdgcn_mfma_f32_16x16x32_bf16(
                        al[ni], bh[mi], acc[mi][ni], 0, 0, 0);
                    acc[mi][ni] = __builtin_amdgcn_mfma_f32_16x16x32_bf16(
                        ah[ni], bl[mi], acc[mi][ni], 0, 0, 0);
                }
        }
        __syncthreads();
    }

    const int nbase = bm * 128 + wr * 64 + (lane >> 4) * 4;
    const int mbase = bn * 128 + wc * 64 + (lane & 15);
    #pragma unroll
    for (int mi = 0; mi < 4; mi++) {
        int m = mbase + mi * 16;
        #pragma unroll
        for (int ni = 0; ni < 4; ni++) {
            int n0 = nbase + ni * 16;
            #pragma unroll
            for (int j = 0; j < 4; j++)
                Yc[(size_t)(n0 + j) * 512 + m] = acc[mi][ni][j];
        }
    }
}

// ---------------- FALLBACK GEMMs (round-3 verbatim, f32 x in-kernel convert)
__global__ __launch_bounds__(256) void k_gemm(
    const float* __restrict__ x, const unsigned short* __restrict__ Wbf,
    unsigned short* __restrict__ Ybv, int N)
{
    __shared__ uint4 As[1024];
    __shared__ uint4 Bs[1024];

    const int t = threadIdx.x;
    const int bm = blockIdx.x, bn = blockIdx.y;
    const int row = t >> 1, half = t & 1;
    const int ga = bm * 128 + row;
    const int gb = bn * 128 + row;
    const int lane = t & 63;
    const int w = t >> 6;
    const int wr = w >> 1, wc = w & 1;

    f32x4 acc[4][4];
    #pragma unroll
    for (int i = 0; i < 4; i++)
        #pragma unroll
        for (int j = 0; j < 4; j++) acc[i][j] = (f32x4){0.f, 0.f, 0.f, 0.f};

    for (int kt = 0; kt < 512; kt += 64) {
        const float4* ax = (const float4*)(x + (size_t)ga * 512 + kt + half * 32);
        #pragma unroll
        for (int c = 0; c < 4; c++) {
            float4 f0, f1;
            if (ga < N) { f0 = ax[c * 2]; f1 = ax[c * 2 + 1]; }
            else { f0 = make_float4(0.f, 0.f, 0.f, 0.f); f1 = f0; }
            uint4 p;
            p.x = (unsigned)f2bf(f0.x) | ((unsigned)f2bf(f0.y) << 16);
            p.y = (unsigned)f2bf(f0.z) | ((unsigned)f2bf(f0.w) << 16);
            p.z = (unsigned)f2bf(f1.x) | ((unsigned)f2bf(f1.y) << 16);
            p.w = (unsigned)f2bf(f1.z) | ((unsigned)f2bf(f1.w) << 16);
            int k8 = half * 4 + c;
            As[row * 8 + (k8 ^ (row & 7))] = p;
        }
        const uint4* bw = (const uint4*)(Wbf + (size_t)gb * 512 + kt + half * 32);
        #pragma unroll
        for (int c = 0; c < 4; c++) {
            uint4 p = bw[c];
            int k8 = half * 4 + c;
            Bs[row * 8 + (k8 ^ (row & 7))] = p;
        }
        __syncthreads();
        #pragma unroll
        for (int kk = 0; kk < 2; kk++) {
            bf16x8 a[4], b[4];
            #pragma unroll
            for (int ni = 0; ni < 4; ni++) {
                int ar = wr * 64 + ni * 16 + (lane & 15);
                int k8 = kk * 4 + (lane >> 4);
                a[ni] = __builtin_bit_cast(bf16x8, As[ar * 8 + (k8 ^ (ar & 7))]);
            }
            #pragma unroll
            for (int mi = 0; mi < 4; mi++) {
                int br = wc * 64 + mi * 16 + (lane & 15);
                int k8 = kk * 4 + (lane >> 4);
                b[mi] = __builtin_bit_cast(bf16x8, Bs[br * 8 + (k8 ^ (br & 7))]);
            }
            #pragma unroll
            for (int mi = 0; mi < 4; mi++)
                #pragma unroll
                for (int ni = 0; ni < 4; ni++)
                    acc[mi][ni] = __builtin_amdgcn_mfma_f32_16x16x32_bf16(
                        a[ni], b[mi], acc[mi][ni], 0, 0, 0);
        }
        __syncthreads();
    }

    const int nbase = bm * 128 + wr * 64 + (lane >> 4) * 4;
    const int mbase = bn * 128 + wc * 64 + (lane & 15);
    #pragma unroll
    for (int mi = 0; mi < 4; mi++) {
        int m = mbase + mi * 16;
        #pragma unroll
        for (int ni = 0; ni < 4; ni++) {
            int n0 = nbase + ni * 16;
            #pragma unroll
            for (int j = 0; j < 4; j++)
                Ybv[(size_t)(n0 + j) * 1024 + m] = f2bf(acc[mi][ni][j]);
        }
    }
}

__global__ __launch_bounds__(256) void k_gemm_split(
    const float* __restrict__ x, const unsigned short* __restrict__ Wbf,
    const unsigned short* __restrict__ Wlo, float* __restrict__ Yc, int N)
{
    __shared__ uint4 Ah[1024], Al[1024], Bh[1024], Bl[1024];

    const int t = threadIdx.x;
    const int bm = blockIdx.x, bn = blockIdx.y;
    const int row = t >> 1, half = t & 1;
    const int ga = bm * 128 + row;
    const int gb = bn * 128 + row;
    const int lane = t & 63;
    const int w = t >> 6;
    const int wr = w >> 1, wc = w & 1;

    f32x4 acc[4][4];
    #pragma unroll
    for (int i = 0; i < 4; i++)
        #pragma unroll
        for (int j = 0; j < 4; j++) acc[i][j] = (f32x4){0.f, 0.f, 0.f, 0.f};

    for (int kt = 0; kt < 512; kt += 64) {
        const float4* ax = (const float4*)(x + (size_t)ga * 512 + kt + half * 32);
        #pragma unroll
        for (int c = 0; c < 4; c++) {
            float4 f0, f1;
            if (ga < N) { f0 = ax[c * 2]; f1 = ax[c * 2 + 1]; }
            else { f0 = make_float4(0.f, 0.f, 0.f, 0.f); f1 = f0; }
            float fs[8] = {f0.x, f0.y, f0.z, f0.w, f1.x, f1.y, f1.z, f1.w};
            unsigned short h[8], l[8];
            #pragma unroll
            for (int j = 0; j < 8; j++) {
                h[j] = f2bf(fs[j]);
                l[j] = f2bf(fs[j] - bf2f(h[j]));
            }
            uint4 ph, pl;
            ph.x = (unsigned)h[0] | ((unsigned)h[1] << 16);
            ph.y = (unsigned)h[2] | ((unsigned)h[3] << 16);
            ph.z = (unsigned)h[4] | ((unsigned)h[5] << 16);
            ph.w = (unsigned)h[6] | ((unsigned)h[7] << 16);
            pl.x = (unsigned)l[0] | ((unsigned)l[1] << 16);
            pl.y = (unsigned)l[2] | ((unsigned)l[3] << 16);
            pl.z = (unsigned)l[4] | ((unsigned)l[5] << 16);
            pl.w = (unsigned)l[6] | ((unsigned)l[7] << 16);
            int k8 = half * 4 + c;
            int sw = row * 8 + (k8 ^ (row & 7));
            Ah[sw] = ph; Al[sw] = pl;
        }
        const uint4* bwh = (const uint4*)(Wbf + (size_t)(1024 + gb) * 512 + kt + half * 32);
        const uint4* bwl = (const uint4*)(Wlo + (size_t)gb * 512 + kt + half * 32);
        #pragma unroll
        for (int c = 0; c < 4; c++) {
            int k8 = half * 4 + c;
            int sw = row * 8 + (k8 ^ (row & 7));
            Bh[sw] = bwh[c];
            Bl[sw] = bwl[c];
        }
        __syncthreads();
        #pragma unroll
        for (int kk = 0; kk < 2; kk++) {
            bf16x8 ah[4], al[4], bh[4], bl[4];
            #pragma unroll
            for (int ni = 0; ni < 4; ni++) {
                int ar = wr * 64 + ni * 16 + (lane & 15);
                int k8 = kk * 4 + (lane >> 4);
                int sw = ar * 8 + (k8 ^ (ar & 7));
                ah[ni] = __builtin_bit_cast(bf16x8, Ah[sw]);
                al[ni] = __builtin_bit_cast(bf16x8, Al[sw]);
            }
            #pragma unroll
            for (int mi = 0; mi < 4; mi++) {
                int br = wc * 64 + mi * 16 + (lane & 15);
                int k8 = kk * 4 + (lane >> 4);
                int sw = br * 8 + (k8 ^ (br & 7));
                bh[mi] = __builtin_bit_cast(bf16x8, Bh[sw]);
                bl[mi] = __builtin_bit_cast(bf16x8, Bl[sw]);
            }
            #pragma unroll
            for (int mi = 0; mi < 4; mi++)
                #pragma unroll
                for (int ni = 0; ni < 4; ni++) {
                    acc[mi][ni] = __builtin_amdgcn_mfma_f32_16x16x32_bf16(
                        ah[ni], bh[mi], acc[mi][ni], 0, 0, 0);
                    acc[mi][ni] = __builtin_amdgcn_mfma_f32_16x16x32_bf16(
                        al[ni], bh[mi], acc[mi][ni], 0, 0, 0);
                    acc[mi][ni] = __builtin_amdgcn_mfma_f32_16x16x32_bf16(
                        ah[ni], bl[mi], acc[mi][ni], 0, 0, 0);
                }
        }
        __syncthreads();
    }

    const int nbase = bm * 128 + wr * 64 + (lane >> 4) * 4;
    const int mbase = bn * 128 + wc * 64 + (lane & 15);
    #pragma unroll
    for (int mi = 0; mi < 4; mi++) {
        int m = mbase + mi * 16;
        #pragma unroll
        for (int ni = 0; ni < 4; ni++) {
            int n0 = nbase + ni * 16;
            #pragma unroll
            for (int j = 0; j < 4; j++)
                Yc[(size_t)(n0 + j) * 512 + m] = acc[mi][ni][j];
        }
    }
}

// ---------------- fused gather: one wave per node
__global__ __launch_bounds__(256) void k_gather(
    const int* __restrict__ ptr, const int* __restrict__ cidx,
    const float* __restrict__ dinv,
    const unsigned short* __restrict__ Ybv, const float* __restrict__ Yc,
    const float* __restrict__ att, const float* __restrict__ bias,
    float* __restrict__ out, int N)
{
    int node = blockIdx.x * 4 + (threadIdx.x >> 6);
    if (node >= N) return;
    int lane = threadIdx.x & 63;

    float a[8];
    {
        const float4* bp = (const float4*)(bias + lane * 8);
        float4 q0 = bp[0], q1 = bp[1];
        a[0] = q0.x; a[1] = q0.y; a[2] = q0.z; a[3] = q0.w;
        a[4] = q1.x; a[5] = q1.y; a[6] = q1.z; a[7] = q1.w;
    }

    float di = dinv[node];
    {
        uint4 v = *((const uint4*)(Ybv + (size_t)node * 1024) + lane);
        float d2 = di * di;
        a[0] += d2 * bf2f((unsigned short)(v.x & 0xffff));
        a[1] += d2 * bf2f((unsigned short)(v.x >> 16));
        a[2] += d2 * bf2f((unsigned short)(v.y & 0xffff));
        a[3] += d2 * bf2f((unsigned short)(v.y >> 16));
        a[4] += d2 * bf2f((unsigned short)(v.z & 0xffff));
        a[5] += d2 * bf2f((unsigned short)(v.z >> 16));
        a[6] += d2 * bf2f((unsigned short)(v.w & 0xffff));
        a[7] += d2 * bf2f((unsigned short)(v.w >> 16));
    }
    {
        int e0 = ptr[node], e1 = ptr[node + 1];
        for (int e = e0; e < e1; ++e) {
            int c = cidx[e];
            float nrm = di * dinv[c];
            uint4 v = *((const uint4*)(Ybv + (size_t)c * 1024) + lane);
            a[0] += nrm * bf2f((unsigned short)(v.x & 0xffff));
            a[1] += nrm * bf2f((unsigned short)(v.x >> 16));
            a[2] += nrm * bf2f((unsigned short)(v.y & 0xffff));
            a[3] += nrm * bf2f((unsigned short)(v.y >> 16));
            a[4] += nrm * bf2f((unsigned short)(v.z & 0xffff));
            a[5] += nrm * bf2f((unsigned short)(v.z >> 16));
            a[6] += nrm * bf2f((unsigned short)(v.w & 0xffff));
            a[7] += nrm * bf2f((unsigned short)(v.w >> 16));
        }
    }
    {
        int e0 = ptr[N + node], e1 = ptr[N + node + 1];
        float vsc = 1.0f / (float)((e1 - e0) > 1 ? (e1 - e0) : 1);
        for (int e = e0; e < e1; ++e) {
            int c = cidx[e];
            uint4 v = *((const uint4*)(Ybv + (size_t)c * 1024 + 512) + lane);
            a[0] += vsc * bf2f((unsigned short)(v.x & 0xffff));
            a[1] += vsc * bf2f((unsigned short)(v.x >> 16));
            a[2] += vsc * bf2f((unsigned short)(v.y & 0xffff));
            a[3] += vsc * bf2f((unsigned short)(v.y >> 16));
            a[4] += vsc * bf2f((unsigned short)(v.z & 0xffff));
            a[5] += vsc * bf2f((unsigned short)(v.z >> 16));
            a[6] += vsc * bf2f((unsigned short)(v.w & 0xffff));
            a[7] += vsc * bf2f((unsigned short)(v.w >> 16));
        }
    }
    {
        int e0 = ptr[2 * N + node], e1 = ptr[2 * N + node + 1];
        if (e0 < e1) {
            const float4* ap = (const float4*)att + lane * 2;
            float4 t0 = ap[0], t1 = ap[1];
            const float4* yr = (const float4*)(Yc + (size_t)node * 512) + lane * 2;
            float4 r0 = yr[0], r1 = yr[1];
            float p[8];
            p[0] = r0.x * t0.x * t0.x; p[1] = r0.y * t0.y * t0.y;
            p[2] = r0.z * t0.z * t0.z; p[3] = r0.w * t0.w * t0.w;
            p[4] = r1.x * t1.x * t1.x; p[5] = r1.y * t1.y * t1.y;
            p[6] = r1.z * t1.z * t1.z; p[7] = r1.w * t1.w * t1.w;
            for (int e = e0; e < e1; ++e) {
                int c = cidx[e];
                const float4* yp = (const float4*)(Yc + (size_t)c * 512) + lane * 2;
                float4 c0 = yp[0], c1 = yp[1];
                float dot = p[0] * c0.x + p[1] * c0.y + p[2] * c0.z + p[3] * c0.w
                          + p[4] * c1.x + p[5] * c1.y + p[6] * c1.z + p[7] * c1.w;
                #pragma unroll
                for (int off = 32; off > 0; off >>= 1) dot += __shfl_xor(dot, off);
                float alpha = 1.0f / (1.0f + expf(-dot));
                a[0] += alpha * c0.x; a[1] += alpha * c0.y;
                a[2] += alpha * c0.z; a[3] += alpha * c0.w;
                a[4] += alpha * c1.x; a[5] += alpha * c1.y;
                a[6] += alpha * c1.z; a[7] += alpha * c1.w;
            }
        }
    }
    float4 o0 = make_float4(a[0], a[1], a[2], a[3]);
    float4 o1 = make_float4(a[4], a[5], a[6], a[7]);
    float4* dst = (float4*)(out + (size_t)node * 512 + lane * 8);
    dst[0] = o0; dst[1] = o1;
}

extern "C" void kernel_launch(void* const* d_in, const int* in_sizes, int n_in,
                              void* d_out, int out_size, void* d_ws, size_t ws_size,
                              hipStream_t stream) {
    const float* x    = (const float*)d_in[0];
    const int*   eb   = (const int*)d_in[1];
    const int*   ev   = (const int*)d_in[2];
    const int*   ec   = (const int*)d_in[3];
    const float* Wb   = (const float*)d_in[4];
    const float* Wv   = (const float*)d_in[5];
    const float* Wc   = (const float*)d_in[6];
    const float* att  = (const float*)d_in[7];
    const float* bias = (const float*)d_in[8];
    float* out = (float*)d_out;

    const int N  = in_sizes[0] / 512;
    const int Eb = in_sizes[1] / 2;
    const int Ev = in_sizes[2] / 2;
    const int Ec = in_sizes[3] / 2;
    const int Etot = Eb + Ev + Ec;
    const int nbm = (N + 127) / 128;
    const size_t Npad = (size_t)nbm * 128;
    const int M = 3 * N;
    const int nScanBlocks = (M + 1023) / 1024;

    char* p = (char*)d_ws;
    unsigned short* Ybv = (unsigned short*)p; p += Npad * 1024 * 2;
    float*          Yc  = (float*)p;          p += Npad * 512 * 4;
    unsigned short* Wbf = (unsigned short*)p; p += (size_t)1536 * 512 * 2;
    unsigned short* Wlo = (unsigned short*)p; p += (size_t)512 * 512 * 2;
    int* cnt  = (int*)p; p += ((size_t)M * 4 + 255) & ~(size_t)255;
    int* ptr_ = (int*)p; p += ((size_t)(M + 1) * 4 + 255) & ~(size_t)255;
    int* cur  = (int*)p; p += ((size_t)M * 4 + 255) & ~(size_t)255;
    int* bsum = (int*)p; p += 256 * 4;
    int* cidx = (int*)p; p += ((size_t)Etot * 4 + 255) & ~(size_t)255;
    float* dinv = (float*)p; p += ((size_t)N * 4 + 255) & ~(size_t)255;
    // fast-path extras
    unsigned short* xh = (unsigned short*)p; p += Npad * 512 * 2;
    unsigned short* xl = (unsigned short*)p; p += Npad * 512 * 2;
    const bool fast = ((size_t)(p - (char*)d_ws) <= ws_size);

    // --- CSR build ---
    hipMemsetAsync(cnt, 0, (size_t)M * 4, stream);
    k_hist<<<(Eb + 255) / 256, 256, 0, stream>>>(eb, Eb, cnt, 0);
    k_hist<<<(Ev + 255) / 256, 256, 0, stream>>>(ev, Ev, cnt, N);
    k_hist<<<(Ec + 255) / 256, 256, 0, stream>>>(ec, Ec, cnt, 2 * N);
    k_scan_a<<<nScanBlocks, 256, 0, stream>>>(cnt, ptr_, bsum, M);
    k_scan_b<<<1, 256, 0, stream>>>(bsum, nScanBlocks);
    k_scan_c<<<(M + 255) / 256, 256, 0, stream>>>(ptr_, bsum, cur, M, Etot);
    k_dinv<<<(N + 255) / 256, 256, 0, stream>>>(cnt, dinv, N);
    k_scatter<<<(Eb + 255) / 256, 256, 0, stream>>>(eb, Eb, cur, cidx, 0);
    k_scatter<<<(Ev + 255) / 256, 256, 0, stream>>>(ev, Ev, cur, cidx, N);
    k_scatter<<<(Ec + 255) / 256, 256, 0, stream>>>(ec, Ec, cur, cidx, 2 * N);

    // --- weights + GEMMs ---
    k_convert_w<<<(1536 * 512 + 255) / 256, 256, 0, stream>>>(Wb, Wv, Wc, Wbf, Wlo);
    if (fast) {
        size_t total = Npad * 512, valid = (size_t)N * 512;
        k_split_x<<<(int)((total / 4 + 255) / 256), 256, 0, stream>>>(x, xh, xl, valid, total);
        k_gemm_f<<<dim3(nbm, 8), 256, 0, stream>>>(xh, Wbf, Ybv, N);
        k_gemm_split_f<<<dim3(nbm, 4), 256, 0, stream>>>(xh, xl, Wbf, Wlo, Yc, N);
    } else {
        k_gemm<<<dim3(nbm, 8), 256, 0, stream>>>(x, Wbf, Ybv, N);
        k_gemm_split<<<dim3(nbm, 4), 256, 0, stream>>>(x, Wbf, Wlo, Yc, N);
    }

    // --- fused gather ---
    k_gather<<<(N + 3) / 4, 256, 0, stream>>>(ptr_, cidx, dinv, Ybv, Yc, att, bias, out, N);
}

// Round 5
// 573.127 us; speedup vs baseline: 29.2255x; 1.1043x over previous
//
#include <hip/hip_runtime.h>
#include <stdint.h>

typedef _Float16 f16x8 __attribute__((ext_vector_type(8)));
typedef float f32x4 __attribute__((ext_vector_type(4)));

__device__ __forceinline__ unsigned short f2h(float f) {
    _Float16 h = (_Float16)f;
    return __builtin_bit_cast(unsigned short, h);
}
__device__ __forceinline__ float h2f(unsigned short s) {
    _Float16 h = __builtin_bit_cast(_Float16, s);
    return (float)h;
}

__device__ __forceinline__ void gload16(const void* g, void* lds) {
    __builtin_amdgcn_global_load_lds(
        (const __attribute__((address_space(1))) void*)g,
        (__attribute__((address_space(3))) void*)lds, 16, 0, 0);
}

// ---------------- W conversion: stack [W_bond; W_vin; W_vconn] as fp16 [1536][512]
__global__ __launch_bounds__(256) void k_convert_w(
    const float* __restrict__ Wb, const float* __restrict__ Wv,
    const float* __restrict__ Wc, unsigned short* __restrict__ Wf)
{
    int idx = blockIdx.x * 256 + threadIdx.x;
    if (idx >= 1536 * 512) return;
    int m = idx >> 9, k = idx & 511;
    float s;
    if (m < 512)       s = Wb[m * 512 + k];
    else if (m < 1024) s = Wv[(m - 512) * 512 + k];
    else               s = Wc[(m - 1024) * 512 + k];
    Wf[idx] = f2h(s);
}

// ---------------- x conversion: f32 -> fp16, zero-padded to Npad rows
__global__ __launch_bounds__(256) void k_conv_x(
    const float* __restrict__ x, unsigned short* __restrict__ xf,
    size_t valid, size_t total)
{
    size_t idx = ((size_t)blockIdx.x * 256 + threadIdx.x) * 4;
    if (idx >= total) return;
    ushort4 h;
    if (idx < valid) {
        float4 f = *(const float4*)(x + idx);
        h.x = f2h(f.x); h.y = f2h(f.y); h.z = f2h(f.z); h.w = f2h(f.w);
    } else {
        h.x = h.y = h.z = h.w = 0;
    }
    *(ushort4*)(xf + idx) = h;
}

// ---------------- CSR build ----------------
__global__ __launch_bounds__(256) void k_hist(
    const int* __restrict__ e, int E, int* __restrict__ cnt, int off)
{
    int i = blockIdx.x * 256 + threadIdx.x;
    if (i < E) atomicAdd(cnt + off + e[i], 1);
}

__global__ __launch_bounds__(256) void k_scan_a(
    const int* __restrict__ cnt, int* __restrict__ ptr, int* __restrict__ bsum, int M)
{
    __shared__ int sh[256];
    int t = threadIdx.x;
    int base = blockIdx.x * 1024 + t * 4;
    int v[4];
    #pragma unroll
    for (int j = 0; j < 4; j++) v[j] = (base + j < M) ? cnt[base + j] : 0;
    int local = v[0] + v[1] + v[2] + v[3];
    sh[t] = local; __syncthreads();
    #pragma unroll
    for (int off = 1; off < 256; off <<= 1) {
        int x = (t >= off) ? sh[t - off] : 0;
        __syncthreads();
        sh[t] += x;
        __syncthreads();
    }
    int run = sh[t] - local;
    #pragma unroll
    for (int j = 0; j < 4; j++) {
        if (base + j < M) ptr[base + j] = run;
        run += v[j];
    }
    if (t == 255) bsum[blockIdx.x] = sh[255];
}

__global__ __launch_bounds__(256) void k_scan_b(int* __restrict__ bsum, int nb)
{
    __shared__ int sh[256];
    int t = threadIdx.x;
    int v = (t < nb) ? bsum[t] : 0;
    sh[t] = v; __syncthreads();
    #pragma unroll
    for (int off = 1; off < 256; off <<= 1) {
        int x = (t >= off) ? sh[t - off] : 0;
        __syncthreads();
        sh[t] += x;
        __syncthreads();
    }
    if (t < nb) bsum[t] = sh[t] - v;
}

__global__ __launch_bounds__(256) void k_scan_c(
    int* __restrict__ ptr, const int* __restrict__ bsum, int* __restrict__ cur,
    int M, int total)
{
    int idx = blockIdx.x * 256 + threadIdx.x;
    if (idx < M) {
        int p = ptr[idx] + bsum[idx >> 10];
        ptr[idx] = p;
        cur[idx] = p;
    }
    if (idx == 0) ptr[M] = total;
}

__global__ __launch_bounds__(256) void k_dinv(
    const int* __restrict__ cnt, float* __restrict__ dinv, int N)
{
    int n = blockIdx.x * 256 + threadIdx.x;
    if (n < N) dinv[n] = rsqrtf((float)(cnt[n] + 1));
}

__global__ __launch_bounds__(256) void k_scatter(
    const int* __restrict__ e, int E, int* __restrict__ cur,
    int* __restrict__ cidx, int off)
{
    int i = blockIdx.x * 256 + threadIdx.x;
    if (i >= E) return;
    int r = e[i], c = e[E + i];
    int pos = atomicAdd(cur + off + r, 1);
    cidx[pos] = c;
}

// ---------------- UNIFIED fp16 GEMM: Y[n,m] = sum_k x[n,k] * Wst[m,k]
// 128x128 tile, BK=64, 4 waves, 16x16x32 f16 MFMA, global_load_lds staging
// with pre-swizzled global source + linear LDS dest.
// bn 0..7 -> Ybv fp16 [Npad][1024]; bn 8..11 -> Yc f32 [Npad][512]
__global__ __launch_bounds__(256) void k_gemm_f(
    const unsigned short* __restrict__ xf, const unsigned short* __restrict__ Wf,
    unsigned short* __restrict__ Ybv, float* __restrict__ Yc)
{
    __shared__ uint4 As[1024];
    __shared__ uint4 Bs[1024];

    const int t = threadIdx.x;
    const int lane = t & 63;
    const int w = t >> 6;
    const int wr = w >> 1, wc = w & 1;
    const int bm = blockIdx.x, bn = blockIdx.y;
    const int rA = lane >> 3;     // row within 8-row segment
    const int cs = lane & 7;      // LDS chunk slot

    f32x4 acc[4][4];
    #pragma unroll
    for (int i = 0; i < 4; i++)
        #pragma unroll
        for (int j = 0; j < 4; j++) acc[i][j] = (f32x4){0.f, 0.f, 0.f, 0.f};

    const size_t baseA = (size_t)bm * 128 * 512;
    const size_t baseB = (size_t)bn * 128 * 512;

    for (int kt = 0; kt < 512; kt += 64) {
        #pragma unroll
        for (int j = 0; j < 4; j++) {
            int seg = w * 4 + j;
            int r = seg * 8 + rA;
            int cg = cs ^ (r & 7);
            gload16(xf + baseA + (size_t)r * 512 + kt + cg * 8, &As[seg * 64]);
            gload16(Wf + baseB + (size_t)r * 512 + kt + cg * 8, &Bs[seg * 64]);
        }
        __syncthreads();
        #pragma unroll
        for (int kk = 0; kk < 2; kk++) {
            f16x8 a[4], b[4];
            #pragma unroll
            for (int ni = 0; ni < 4; ni++) {
                int ar = wr * 64 + ni * 16 + (lane & 15);
                int k8 = kk * 4 + (lane >> 4);
                a[ni] = __builtin_bit_cast(f16x8, As[ar * 8 + (k8 ^ (ar & 7))]);
            }
            #pragma unroll
            for (int mi = 0; mi < 4; mi++) {
                int br = wc * 64 + mi * 16 + (lane & 15);
                int k8 = kk * 4 + (lane >> 4);
                b[mi] = __builtin_bit_cast(f16x8, Bs[br * 8 + (k8 ^ (br & 7))]);
            }
            #pragma unroll
            for (int mi = 0; mi < 4; mi++)
                #pragma unroll
                for (int ni = 0; ni < 4; ni++)
                    acc[mi][ni] = __builtin_amdgcn_mfma_f32_16x16x32_f16(
                        a[ni], b[mi], acc[mi][ni], 0, 0, 0);
        }
        __syncthreads();
    }

    const int nbase = bm * 128 + wr * 64 + (lane >> 4) * 4;
    const int mbase = bn * 128 + wc * 64 + (lane & 15);
    if (bn < 8) {
        #pragma unroll
        for (int mi = 0; mi < 4; mi++) {
            int m = mbase + mi * 16;
            #pragma unroll
            for (int ni = 0; ni < 4; ni++) {
                int n0 = nbase + ni * 16;
                #pragma unroll
                for (int j = 0; j < 4; j++)
                    Ybv[(size_t)(n0 + j) * 1024 + m] = f2h(acc[mi][ni][j]);
            }
        }
    } else {
        #pragma unroll
        for (int mi = 0; mi < 4; mi++) {
            int m = mbase + mi * 16 - 1024;
            #pragma unroll
            for (int ni = 0; ni < 4; ni++) {
                int n0 = nbase + ni * 16;
                #pragma unroll
                for (int j = 0; j < 4; j++)
                    Yc[(size_t)(n0 + j) * 512 + m] = acc[mi][ni][j];
            }
        }
    }
}

// ---------------- fused gather: one wave per node, chunk-4 pipelined
__device__ __forceinline__ void acc_h8(float* a, uint4 v, float s) {
    a[0] += s * h2f((unsigned short)(v.x & 0xffff));
    a[1] += s * h2f((unsigned short)(v.x >> 16));
    a[2] += s * h2f((unsigned short)(v.y & 0xffff));
    a[3] += s * h2f((unsigned short)(v.y >> 16));
    a[4] += s * h2f((unsigned short)(v.z & 0xffff));
    a[5] += s * h2f((unsigned short)(v.z >> 16));
    a[6] += s * h2f((unsigned short)(v.w & 0xffff));
    a[7] += s * h2f((unsigned short)(v.w >> 16));
}

__global__ __launch_bounds__(256) void k_gather(
    const int* __restrict__ ptr, const int* __restrict__ cidx,
    const float* __restrict__ dinv,
    const unsigned short* __restrict__ Ybv, const float* __restrict__ Yc,
    const float* __restrict__ att, const float* __restrict__ bias,
    float* __restrict__ out, int N)
{
    int node = blockIdx.x * 4 + (threadIdx.x >> 6);
    if (node >= N) return;
    int lane = threadIdx.x & 63;

    float a[8];
    {
        const float4* bp = (const float4*)(bias + lane * 8);
        float4 q0 = bp[0], q1 = bp[1];
        a[0] = q0.x; a[1] = q0.y; a[2] = q0.z; a[3] = q0.w;
        a[4] = q1.x; a[5] = q1.y; a[6] = q1.z; a[7] = q1.w;
    }

    float di = dinv[node];
    // self loop (bond)
    {
        uint4 v = *((const uint4*)(Ybv + (size_t)node * 1024) + lane);
        acc_h8(a, v, di * di);
    }
    // bond edges, chunk-4 pipelined
    {
        int e0 = ptr[node], e1 = ptr[node + 1];
        int e = e0;
        for (; e + 4 <= e1; e += 4) {
            int c0 = cidx[e], c1 = cidx[e + 1], c2 = cidx[e + 2], c3 = cidx[e + 3];
            uint4 v0 = *((const uint4*)(Ybv + (size_t)c0 * 1024) + lane);
            uint4 v1 = *((const uint4*)(Ybv + (size_t)c1 * 1024) + lane);
            uint4 v2 = *((const uint4*)(Ybv + (size_t)c2 * 1024) + lane);
            uint4 v3 = *((const uint4*)(Ybv + (size_t)c3 * 1024) + lane);
            float n0 = di * dinv[c0], n1 = di * dinv[c1];
            float n2 = di * dinv[c2], n3 = di * dinv[c3];
            acc_h8(a, v0, n0); acc_h8(a, v1, n1);
            acc_h8(a, v2, n2); acc_h8(a, v3, n3);
        }
        for (; e < e1; ++e) {
            int c = cidx[e];
            uint4 v = *((const uint4*)(Ybv + (size_t)c * 1024) + lane);
            acc_h8(a, v, di * dinv[c]);
        }
    }
    // vin edges (mean), chunk-4
    {
        int e0 = ptr[N + node], e1 = ptr[N + node + 1];
        float vsc = 1.0f / (float)((e1 - e0) > 1 ? (e1 - e0) : 1);
        int e = e0;
        for (; e + 4 <= e1; e += 4) {
            int c0 = cidx[e], c1 = cidx[e + 1], c2 = cidx[e + 2], c3 = cidx[e + 3];
            uint4 v0 = *((const uint4*)(Ybv + (size_t)c0 * 1024 + 512) + lane);
            uint4 v1 = *((const uint4*)(Ybv + (size_t)c1 * 1024 + 512) + lane);
            uint4 v2 = *((const uint4*)(Ybv + (size_t)c2 * 1024 + 512) + lane);
            uint4 v3 = *((const uint4*)(Ybv + (size_t)c3 * 1024 + 512) + lane);
            acc_h8(a, v0, vsc); acc_h8(a, v1, vsc);
            acc_h8(a, v2, vsc); acc_h8(a, v3, vsc);
        }
        for (; e < e1; ++e) {
            int c = cidx[e];
            uint4 v = *((const uint4*)(Ybv + (size_t)c * 1024 + 512) + lane);
            acc_h8(a, v, vsc);
        }
    }
    // conn edges (sigmoid dot attention), chunk-4
    {
        int e0 = ptr[2 * N + node], e1 = ptr[2 * N + node + 1];
        if (e0 < e1) {
            const float4* ap = (const float4*)att + lane * 2;
            float4 t0 = ap[0], t1 = ap[1];
            const float4* yr = (const float4*)(Yc + (size_t)node * 512) + lane * 2;
            float4 r0 = yr[0], r1 = yr[1];
            float p0 = r0.x * t0.x * t0.x, p1 = r0.y * t0.y * t0.y;
            float p2 = r0.z * t0.z * t0.z, p3 = r0.w * t0.w * t0.w;
            float p4 = r1.x * t1.x * t1.x, p5 = r1.y * t1.y * t1.y;
            float p6 = r1.z * t1.z * t1.z, p7 = r1.w * t1.w * t1.w;
            int e = e0;
            for (; e + 4 <= e1; e += 4) {
                int c0 = cidx[e], c1 = cidx[e + 1], c2 = cidx[e + 2], c3 = cidx[e + 3];
                const float4* y0 = (const float4*)(Yc + (size_t)c0 * 512) + lane * 2;
                const float4* y1 = (const float4*)(Yc + (size_t)c1 * 512) + lane * 2;
                const float4* y2 = (const float4*)(Yc + (size_t)c2 * 512) + lane * 2;
                const float4* y3 = (const float4*)(Yc + (size_t)c3 * 512) + lane * 2;
                float4 a0 = y0[0], b0 = y0[1];
                float4 a1 = y1[0], b1 = y1[1];
                float4 a2 = y2[0], b2 = y2[1];
                float4 a3 = y3[0], b3 = y3[1];
                float d0 = p0*a0.x + p1*a0.y + p2*a0.z + p3*a0.w + p4*b0.x + p5*b0.y + p6*b0.z + p7*b0.w;
                float d1 = p0*a1.x + p1*a1.y + p2*a1.z + p3*a1.w + p4*b1.x + p5*b1.y + p6*b1.z + p7*b1.w;
                float d2 = p0*a2.x + p1*a2.y + p2*a2.z + p3*a2.w + p4*b2.x + p5*b2.y + p6*b2.z + p7*b2.w;
                float d3 = p0*a3.x + p1*a3.y + p2*a3.z + p3*a3.w + p4*b3.x + p5*b3.y + p6*b3.z + p7*b3.w;
                #pragma unroll
                for (int off = 32; off > 0; off >>= 1) {
                    d0 += __shfl_xor(d0, off);
                    d1 += __shfl_xor(d1, off);
                    d2 += __shfl_xor(d2, off);
                    d3 += __shfl_xor(d3, off);
                }
                float al0 = 1.0f / (1.0f + expf(-d0));
                float al1 = 1.0f / (1.0f + expf(-d1));
                float al2 = 1.0f / (1.0f + expf(-d2));
                float al3 = 1.0f / (1.0f + expf(-d3));
                a[0] += al0*a0.x + al1*a1.x + al2*a2.x + al3*a3.x;
                a[1] += al0*a0.y + al1*a1.y + al2*a2.y + al3*a3.y;
                a[2] += al0*a0.z + al1*a1.z + al2*a2.z + al3*a3.z;
                a[3] += al0*a0.w + al1*a1.w + al2*a2.w + al3*a3.w;
                a[4] += al0*b0.x + al1*b1.x + al2*b2.x + al3*b3.x;
                a[5] += al0*b0.y + al1*b1.y + al2*b2.y + al3*b3.y;
                a[6] += al0*b0.z + al1*b1.z + al2*b2.z + al3*b3.z;
                a[7] += al0*b0.w + al1*b1.w + al2*b2.w + al3*b3.w;
            }
            for (; e < e1; ++e) {
                int c = cidx[e];
                const float4* yp = (const float4*)(Yc + (size_t)c * 512) + lane * 2;
                float4 c0 = yp[0], c1 = yp[1];
                float dot = p0*c0.x + p1*c0.y + p2*c0.z + p3*c0.w
                          + p4*c1.x + p5*c1.y + p6*c1.z + p7*c1.w;
                #pragma unroll
                for (int off = 32; off > 0; off >>= 1) dot += __shfl_xor(dot, off);
                float alpha = 1.0f / (1.0f + expf(-dot));
                a[0] += alpha * c0.x; a[1] += alpha * c0.y;
                a[2] += alpha * c0.z; a[3] += alpha * c0.w;
                a[4] += alpha * c1.x; a[5] += alpha * c1.y;
                a[6] += alpha * c1.z; a[7] += alpha * c1.w;
            }
        }
    }
    float4 o0 = make_float4(a[0], a[1], a[2], a[3]);
    float4 o1 = make_float4(a[4], a[5], a[6], a[7]);
    float4* dst = (float4*)(out + (size_t)node * 512 + lane * 8);
    dst[0] = o0; dst[1] = o1;
}

extern "C" void kernel_launch(void* const* d_in, const int* in_sizes, int n_in,
                              void* d_out, int out_size, void* d_ws, size_t ws_size,
                              hipStream_t stream) {
    const float* x    = (const float*)d_in[0];
    const int*   eb   = (const int*)d_in[1];
    const int*   ev   = (const int*)d_in[2];
    const int*   ec   = (const int*)d_in[3];
    const float* Wb   = (const float*)d_in[4];
    const float* Wv   = (const float*)d_in[5];
    const float* Wc   = (const float*)d_in[6];
    const float* att  = (const float*)d_in[7];
    const float* bias = (const float*)d_in[8];
    float* out = (float*)d_out;

    const int N  = in_sizes[0] / 512;
    const int Eb = in_sizes[1] / 2;
    const int Ev = in_sizes[2] / 2;
    const int Ec = in_sizes[3] / 2;
    const int Etot = Eb + Ev + Ec;
    const int nbm = (N + 127) / 128;
    const size_t Npad = (size_t)nbm * 128;
    const int M = 3 * N;
    const int nScanBlocks = (M + 1023) / 1024;

    char* p = (char*)d_ws;
    unsigned short* Ybv = (unsigned short*)p; p += Npad * 1024 * 2;  // bond|vin fp16
    float*          Yc  = (float*)p;          p += Npad * 512 * 4;   // vconn f32
    unsigned short* Wf  = (unsigned short*)p; p += (size_t)1536 * 512 * 2;
    unsigned short* xf  = (unsigned short*)p; p += Npad * 512 * 2;
    int* cnt  = (int*)p; p += ((size_t)M * 4 + 255) & ~(size_t)255;
    int* ptr_ = (int*)p; p += ((size_t)(M + 1) * 4 + 255) & ~(size_t)255;
    int* cur  = (int*)p; p += ((size_t)M * 4 + 255) & ~(size_t)255;
    int* bsum = (int*)p; p += 256 * 4;
    int* cidx = (int*)p; p += ((size_t)Etot * 4 + 255) & ~(size_t)255;
    float* dinv = (float*)p; p += ((size_t)N * 4 + 255) & ~(size_t)255;

    // --- CSR build ---
    hipMemsetAsync(cnt, 0, (size_t)M * 4, stream);
    k_hist<<<(Eb + 255) / 256, 256, 0, stream>>>(eb, Eb, cnt, 0);
    k_hist<<<(Ev + 255) / 256, 256, 0, stream>>>(ev, Ev, cnt, N);
    k_hist<<<(Ec + 255) / 256, 256, 0, stream>>>(ec, Ec, cnt, 2 * N);
    k_scan_a<<<nScanBlocks, 256, 0, stream>>>(cnt, ptr_, bsum, M);
    k_scan_b<<<1, 256, 0, stream>>>(bsum, nScanBlocks);
    k_scan_c<<<(M + 255) / 256, 256, 0, stream>>>(ptr_, bsum, cur, M, Etot);
    k_dinv<<<(N + 255) / 256, 256, 0, stream>>>(cnt, dinv, N);
    k_scatter<<<(Eb + 255) / 256, 256, 0, stream>>>(eb, Eb, cur, cidx, 0);
    k_scatter<<<(Ev + 255) / 256, 256, 0, stream>>>(ev, Ev, cur, cidx, N);
    k_scatter<<<(Ec + 255) / 256, 256, 0, stream>>>(ec, Ec, cur, cidx, 2 * N);

    // --- conversions + GEMM ---
    k_convert_w<<<(1536 * 512 + 255) / 256, 256, 0, stream>>>(Wb, Wv, Wc, Wf);
    {
        size_t total = Npad * 512, valid = (size_t)N * 512;
        k_conv_x<<<(int)((total / 4 + 255) / 256), 256, 0, stream>>>(x, xf, valid, total);
    }
    k_gemm_f<<<dim3(nbm, 12), 256, 0, stream>>>(xf, Wf, Ybv, Yc);

    // --- fused gather ---
    k_gather<<<(N + 3) / 4, 256, 0, stream>>>(ptr_, cidx, dinv, Ybv, Yc, att, bias, out, N);
}

// Round 6
// 498.515 us; speedup vs baseline: 33.5996x; 1.1497x over previous
//
#include <hip/hip_runtime.h>
#include <stdint.h>

typedef _Float16 f16x8 __attribute__((ext_vector_type(8)));
typedef float f32x4 __attribute__((ext_vector_type(4)));

__device__ __forceinline__ unsigned short f2h(float f) {
    _Float16 h = (_Float16)f;
    return __builtin_bit_cast(unsigned short, h);
}
__device__ __forceinline__ float h2f(unsigned short s) {
    _Float16 h = __builtin_bit_cast(_Float16, s);
    return (float)h;
}

__device__ __forceinline__ void gload16(const void* g, void* lds) {
    __builtin_amdgcn_global_load_lds(
        (const __attribute__((address_space(1))) void*)g,
        (__attribute__((address_space(3))) void*)lds, 16, 0, 0);
}

// ---------------- W conversion: stack [W_bond; W_vin; W_vconn] as fp16 [1536][512]
__global__ __launch_bounds__(256) void k_convert_w(
    const float* __restrict__ Wb, const float* __restrict__ Wv,
    const float* __restrict__ Wc, unsigned short* __restrict__ Wf)
{
    int idx = blockIdx.x * 256 + threadIdx.x;
    if (idx >= 1536 * 512) return;
    int m = idx >> 9, k = idx & 511;
    float s;
    if (m < 512)       s = Wb[m * 512 + k];
    else if (m < 1024) s = Wv[(m - 512) * 512 + k];
    else               s = Wc[(m - 1024) * 512 + k];
    Wf[idx] = f2h(s);
}

// ---------------- x conversion: f32 -> fp16, zero-padded to Npad rows
__global__ __launch_bounds__(256) void k_conv_x(
    const float* __restrict__ x, unsigned short* __restrict__ xf,
    size_t valid, size_t total)
{
    size_t idx = ((size_t)blockIdx.x * 256 + threadIdx.x) * 4;
    if (idx >= total) return;
    ushort4 h;
    if (idx < valid) {
        float4 f = *(const float4*)(x + idx);
        h.x = f2h(f.x); h.y = f2h(f.y); h.z = f2h(f.z); h.w = f2h(f.w);
    } else {
        h.x = h.y = h.z = h.w = 0;
    }
    *(ushort4*)(xf + idx) = h;
}

// ---------------- CSR build ----------------
__global__ __launch_bounds__(256) void k_hist(
    const int* __restrict__ e, int E, int* __restrict__ cnt, int off)
{
    int i = blockIdx.x * 256 + threadIdx.x;
    if (i < E) atomicAdd(cnt + off + e[i], 1);
}

__global__ __launch_bounds__(256) void k_scan_a(
    const int* __restrict__ cnt, int* __restrict__ ptr, int* __restrict__ bsum, int M)
{
    __shared__ int sh[256];
    int t = threadIdx.x;
    int base = blockIdx.x * 1024 + t * 4;
    int v[4];
    #pragma unroll
    for (int j = 0; j < 4; j++) v[j] = (base + j < M) ? cnt[base + j] : 0;
    int local = v[0] + v[1] + v[2] + v[3];
    sh[t] = local; __syncthreads();
    #pragma unroll
    for (int off = 1; off < 256; off <<= 1) {
        int x = (t >= off) ? sh[t - off] : 0;
        __syncthreads();
        sh[t] += x;
        __syncthreads();
    }
    int run = sh[t] - local;
    #pragma unroll
    for (int j = 0; j < 4; j++) {
        if (base + j < M) ptr[base + j] = run;
        run += v[j];
    }
    if (t == 255) bsum[blockIdx.x] = sh[255];
}

__global__ __launch_bounds__(256) void k_scan_b(int* __restrict__ bsum, int nb)
{
    __shared__ int sh[256];
    int t = threadIdx.x;
    int v = (t < nb) ? bsum[t] : 0;
    sh[t] = v; __syncthreads();
    #pragma unroll
    for (int off = 1; off < 256; off <<= 1) {
        int x = (t >= off) ? sh[t - off] : 0;
        __syncthreads();
        sh[t] += x;
        __syncthreads();
    }
    if (t < nb) bsum[t] = sh[t] - v;
}

__global__ __launch_bounds__(256) void k_scan_c(
    int* __restrict__ ptr, const int* __restrict__ bsum, int* __restrict__ cur,
    int M, int total)
{
    int idx = blockIdx.x * 256 + threadIdx.x;
    if (idx < M) {
        int p = ptr[idx] + bsum[idx >> 10];
        ptr[idx] = p;
        cur[idx] = p;
    }
    if (idx == 0) ptr[M] = total;
}

__global__ __launch_bounds__(256) void k_dinv(
    const int* __restrict__ cnt, float* __restrict__ dinv, int N)
{
    int n = blockIdx.x * 256 + threadIdx.x;
    if (n < N) dinv[n] = rsqrtf((float)(cnt[n] + 1));
}

__global__ __launch_bounds__(256) void k_scatter(
    const int* __restrict__ e, int E, int* __restrict__ cur,
    int* __restrict__ cidx, int off)
{
    int i = blockIdx.x * 256 + threadIdx.x;
    if (i >= E) return;
    int r = e[i], c = e[E + i];
    int pos = atomicAdd(cur + off + r, 1);
    cidx[pos] = c;
}

// ---------------- UNIFIED fp16 GEMM: Y[n,m] = sum_k x[n,k] * Wst[m,k]
// bn 0..7 -> Ybv fp16 [Npad][1024]; bn 8..11 -> Ycf fp16 [Npad][512]
__global__ __launch_bounds__(256) void k_gemm_f(
    const unsigned short* __restrict__ xf, const unsigned short* __restrict__ Wf,
    unsigned short* __restrict__ Ybv, unsigned short* __restrict__ Ycf)
{
    __shared__ uint4 As[1024];
    __shared__ uint4 Bs[1024];

    const int t = threadIdx.x;
    const int lane = t & 63;
    const int w = t >> 6;
    const int wr = w >> 1, wc = w & 1;
    const int bm = blockIdx.x, bn = blockIdx.y;
    const int rA = lane >> 3;     // row within 8-row segment
    const int cs = lane & 7;      // LDS chunk slot

    f32x4 acc[4][4];
    #pragma unroll
    for (int i = 0; i < 4; i++)
        #pragma unroll
        for (int j = 0; j < 4; j++) acc[i][j] = (f32x4){0.f, 0.f, 0.f, 0.f};

    const size_t baseA = (size_t)bm * 128 * 512;
    const size_t baseB = (size_t)bn * 128 * 512;

    for (int kt = 0; kt < 512; kt += 64) {
        #pragma unroll
        for (int j = 0; j < 4; j++) {
            int seg = w * 4 + j;
            int r = seg * 8 + rA;
            int cg = cs ^ (r & 7);
            gload16(xf + baseA + (size_t)r * 512 + kt + cg * 8, &As[seg * 64]);
            gload16(Wf + baseB + (size_t)r * 512 + kt + cg * 8, &Bs[seg * 64]);
        }
        __syncthreads();
        #pragma unroll
        for (int kk = 0; kk < 2; kk++) {
            f16x8 a[4], b[4];
            #pragma unroll
            for (int ni = 0; ni < 4; ni++) {
                int ar = wr * 64 + ni * 16 + (lane & 15);
                int k8 = kk * 4 + (lane >> 4);
                a[ni] = __builtin_bit_cast(f16x8, As[ar * 8 + (k8 ^ (ar & 7))]);
            }
            #pragma unroll
            for (int mi = 0; mi < 4; mi++) {
                int br = wc * 64 + mi * 16 + (lane & 15);
                int k8 = kk * 4 + (lane >> 4);
                b[mi] = __builtin_bit_cast(f16x8, Bs[br * 8 + (k8 ^ (br & 7))]);
            }
            #pragma unroll
            for (int mi = 0; mi < 4; mi++)
                #pragma unroll
                for (int ni = 0; ni < 4; ni++)
                    acc[mi][ni] = __builtin_amdgcn_mfma_f32_16x16x32_f16(
                        a[ni], b[mi], acc[mi][ni], 0, 0, 0);
        }
        __syncthreads();
    }

    const int nbase = bm * 128 + wr * 64 + (lane >> 4) * 4;
    const int mbase = bn * 128 + wc * 64 + (lane & 15);
    if (bn < 8) {
        #pragma unroll
        for (int mi = 0; mi < 4; mi++) {
            int m = mbase + mi * 16;
            #pragma unroll
            for (int ni = 0; ni < 4; ni++) {
                int n0 = nbase + ni * 16;
                #pragma unroll
                for (int j = 0; j < 4; j++)
                    Ybv[(size_t)(n0 + j) * 1024 + m] = f2h(acc[mi][ni][j]);
            }
        }
    } else {
        #pragma unroll
        for (int mi = 0; mi < 4; mi++) {
            int m = mbase + mi * 16 - 1024;
            #pragma unroll
            for (int ni = 0; ni < 4; ni++) {
                int n0 = nbase + ni * 16;
                #pragma unroll
                for (int j = 0; j < 4; j++)
                    Ycf[(size_t)(n0 + j) * 512 + m] = f2h(acc[mi][ni][j]);
            }
        }
    }
}

// ---------------- fused gather: one wave per node, chunk-4 pipelined
__device__ __forceinline__ void acc_h8(float* a, uint4 v, float s) {
    a[0] += s * h2f((unsigned short)(v.x & 0xffff));
    a[1] += s * h2f((unsigned short)(v.x >> 16));
    a[2] += s * h2f((unsigned short)(v.y & 0xffff));
    a[3] += s * h2f((unsigned short)(v.y >> 16));
    a[4] += s * h2f((unsigned short)(v.z & 0xffff));
    a[5] += s * h2f((unsigned short)(v.z >> 16));
    a[6] += s * h2f((unsigned short)(v.w & 0xffff));
    a[7] += s * h2f((unsigned short)(v.w >> 16));
}
__device__ __forceinline__ void unp_h8(float* d, uint4 v) {
    d[0] = h2f((unsigned short)(v.x & 0xffff));
    d[1] = h2f((unsigned short)(v.x >> 16));
    d[2] = h2f((unsigned short)(v.y & 0xffff));
    d[3] = h2f((unsigned short)(v.y >> 16));
    d[4] = h2f((unsigned short)(v.z & 0xffff));
    d[5] = h2f((unsigned short)(v.z >> 16));
    d[6] = h2f((unsigned short)(v.w & 0xffff));
    d[7] = h2f((unsigned short)(v.w >> 16));
}

__global__ __launch_bounds__(256) void k_gather(
    const int* __restrict__ ptr, const int* __restrict__ cidx,
    const float* __restrict__ dinv,
    const unsigned short* __restrict__ Ybv, const unsigned short* __restrict__ Ycf,
    const float* __restrict__ att, const float* __restrict__ bias,
    float* __restrict__ out, int N)
{
    int node = blockIdx.x * 4 + (threadIdx.x >> 6);
    if (node >= N) return;
    int lane = threadIdx.x & 63;

    float a[8];
    {
        const float4* bp = (const float4*)(bias + lane * 8);
        float4 q0 = bp[0], q1 = bp[1];
        a[0] = q0.x; a[1] = q0.y; a[2] = q0.z; a[3] = q0.w;
        a[4] = q1.x; a[5] = q1.y; a[6] = q1.z; a[7] = q1.w;
    }

    float di = dinv[node];
    // self loop (bond)
    {
        uint4 v = *((const uint4*)(Ybv + (size_t)node * 1024) + lane);
        acc_h8(a, v, di * di);
    }
    // bond edges, chunk-4 pipelined
    {
        int e0 = ptr[node], e1 = ptr[node + 1];
        int e = e0;
        for (; e + 4 <= e1; e += 4) {
            int c0 = cidx[e], c1 = cidx[e + 1], c2 = cidx[e + 2], c3 = cidx[e + 3];
            uint4 v0 = *((const uint4*)(Ybv + (size_t)c0 * 1024) + lane);
            uint4 v1 = *((const uint4*)(Ybv + (size_t)c1 * 1024) + lane);
            uint4 v2 = *((const uint4*)(Ybv + (size_t)c2 * 1024) + lane);
            uint4 v3 = *((const uint4*)(Ybv + (size_t)c3 * 1024) + lane);
            float n0 = di * dinv[c0], n1 = di * dinv[c1];
            float n2 = di * dinv[c2], n3 = di * dinv[c3];
            acc_h8(a, v0, n0); acc_h8(a, v1, n1);
            acc_h8(a, v2, n2); acc_h8(a, v3, n3);
        }
        for (; e < e1; ++e) {
            int c = cidx[e];
            uint4 v = *((const uint4*)(Ybv + (size_t)c * 1024) + lane);
            acc_h8(a, v, di * dinv[c]);
        }
    }
    // vin edges (mean), chunk-4
    {
        int e0 = ptr[N + node], e1 = ptr[N + node + 1];
        float vsc = 1.0f / (float)((e1 - e0) > 1 ? (e1 - e0) : 1);
        int e = e0;
        for (; e + 4 <= e1; e += 4) {
            int c0 = cidx[e], c1 = cidx[e + 1], c2 = cidx[e + 2], c3 = cidx[e + 3];
            uint4 v0 = *((const uint4*)(Ybv + (size_t)c0 * 1024 + 512) + lane);
            uint4 v1 = *((const uint4*)(Ybv + (size_t)c1 * 1024 + 512) + lane);
            uint4 v2 = *((const uint4*)(Ybv + (size_t)c2 * 1024 + 512) + lane);
            uint4 v3 = *((const uint4*)(Ybv + (size_t)c3 * 1024 + 512) + lane);
            acc_h8(a, v0, vsc); acc_h8(a, v1, vsc);
            acc_h8(a, v2, vsc); acc_h8(a, v3, vsc);
        }
        for (; e < e1; ++e) {
            int c = cidx[e];
            uint4 v = *((const uint4*)(Ybv + (size_t)c * 1024 + 512) + lane);
            acc_h8(a, v, vsc);
        }
    }
    // conn edges (sigmoid dot attention), chunk-4, fp16 rows
    {
        int e0 = ptr[2 * N + node], e1 = ptr[2 * N + node + 1];
        if (e0 < e1) {
            const float4* ap = (const float4*)att + lane * 2;
            float4 t0 = ap[0], t1 = ap[1];
            float yr[8];
            unp_h8(yr, *((const uint4*)(Ycf + (size_t)node * 512) + lane));
            float p0 = yr[0] * t0.x * t0.x, p1 = yr[1] * t0.y * t0.y;
            float p2 = yr[2] * t0.z * t0.z, p3 = yr[3] * t0.w * t0.w;
            float p4 = yr[4] * t1.x * t1.x, p5 = yr[5] * t1.y * t1.y;
            float p6 = yr[6] * t1.z * t1.z, p7 = yr[7] * t1.w * t1.w;
            int e = e0;
            for (; e + 4 <= e1; e += 4) {
                int c0 = cidx[e], c1 = cidx[e + 1], c2 = cidx[e + 2], c3 = cidx[e + 3];
                uint4 u0 = *((const uint4*)(Ycf + (size_t)c0 * 512) + lane);
                uint4 u1 = *((const uint4*)(Ycf + (size_t)c1 * 512) + lane);
                uint4 u2 = *((const uint4*)(Ycf + (size_t)c2 * 512) + lane);
                uint4 u3 = *((const uint4*)(Ycf + (size_t)c3 * 512) + lane);
                float y0[8], y1[8], y2[8], y3[8];
                unp_h8(y0, u0); unp_h8(y1, u1); unp_h8(y2, u2); unp_h8(y3, u3);
                float d0 = p0*y0[0] + p1*y0[1] + p2*y0[2] + p3*y0[3] + p4*y0[4] + p5*y0[5] + p6*y0[6] + p7*y0[7];
                float d1 = p0*y1[0] + p1*y1[1] + p2*y1[2] + p3*y1[3] + p4*y1[4] + p5*y1[5] + p6*y1[6] + p7*y1[7];
                float d2 = p0*y2[0] + p1*y2[1] + p2*y2[2] + p3*y2[3] + p4*y2[4] + p5*y2[5] + p6*y2[6] + p7*y2[7];
                float d3 = p0*y3[0] + p1*y3[1] + p2*y3[2] + p3*y3[3] + p4*y3[4] + p5*y3[5] + p6*y3[6] + p7*y3[7];
                #pragma unroll
                for (int off = 32; off > 0; off >>= 1) {
                    d0 += __shfl_xor(d0, off);
                    d1 += __shfl_xor(d1, off);
                    d2 += __shfl_xor(d2, off);
                    d3 += __shfl_xor(d3, off);
                }
                float al0 = 1.0f / (1.0f + expf(-d0));
                float al1 = 1.0f / (1.0f + expf(-d1));
                float al2 = 1.0f / (1.0f + expf(-d2));
                float al3 = 1.0f / (1.0f + expf(-d3));
                #pragma unroll
                for (int j = 0; j < 8; j++)
                    a[j] += al0*y0[j] + al1*y1[j] + al2*y2[j] + al3*y3[j];
            }
            for (; e < e1; ++e) {
                int c = cidx[e];
                uint4 u = *((const uint4*)(Ycf + (size_t)c * 512) + lane);
                float y[8];
                unp_h8(y, u);
                float dot = p0*y[0] + p1*y[1] + p2*y[2] + p3*y[3]
                          + p4*y[4] + p5*y[5] + p6*y[6] + p7*y[7];
                #pragma unroll
                for (int off = 32; off > 0; off >>= 1) dot += __shfl_xor(dot, off);
                float alpha = 1.0f / (1.0f + expf(-dot));
                #pragma unroll
                for (int j = 0; j < 8; j++) a[j] += alpha * y[j];
            }
        }
    }
    float4 o0 = make_float4(a[0], a[1], a[2], a[3]);
    float4 o1 = make_float4(a[4], a[5], a[6], a[7]);
    float4* dst = (float4*)(out + (size_t)node * 512 + lane * 8);
    dst[0] = o0; dst[1] = o1;
}

extern "C" void kernel_launch(void* const* d_in, const int* in_sizes, int n_in,
                              void* d_out, int out_size, void* d_ws, size_t ws_size,
                              hipStream_t stream) {
    const float* x    = (const float*)d_in[0];
    const int*   eb   = (const int*)d_in[1];
    const int*   ev   = (const int*)d_in[2];
    const int*   ec   = (const int*)d_in[3];
    const float* Wb   = (const float*)d_in[4];
    const float* Wv   = (const float*)d_in[5];
    const float* Wc   = (const float*)d_in[6];
    const float* att  = (const float*)d_in[7];
    const float* bias = (const float*)d_in[8];
    float* out = (float*)d_out;

    const int N  = in_sizes[0] / 512;
    const int Eb = in_sizes[1] / 2;
    const int Ev = in_sizes[2] / 2;
    const int Ec = in_sizes[3] / 2;
    const int Etot = Eb + Ev + Ec;
    const int nbm = (N + 127) / 128;
    const size_t Npad = (size_t)nbm * 128;
    const int M = 3 * N;
    const int nScanBlocks = (M + 1023) / 1024;

    char* p = (char*)d_ws;
    unsigned short* Ybv = (unsigned short*)p; p += Npad * 1024 * 2;  // bond|vin fp16
    unsigned short* Ycf = (unsigned short*)p; p += Npad * 512 * 2;   // vconn fp16
    unsigned short* Wf  = (unsigned short*)p; p += (size_t)1536 * 512 * 2;
    unsigned short* xf  = (unsigned short*)p; p += Npad * 512 * 2;
    int* cnt  = (int*)p; p += ((size_t)M * 4 + 255) & ~(size_t)255;
    int* ptr_ = (int*)p; p += ((size_t)(M + 1) * 4 + 255) & ~(size_t)255;
    int* cur  = (int*)p; p += ((size_t)M * 4 + 255) & ~(size_t)255;
    int* bsum = (int*)p; p += 256 * 4;
    int* cidx = (int*)p; p += ((size_t)Etot * 4 + 255) & ~(size_t)255;
    float* dinv = (float*)p; p += ((size_t)N * 4 + 255) & ~(size_t)255;

    // --- CSR build ---
    hipMemsetAsync(cnt, 0, (size_t)M * 4, stream);
    k_hist<<<(Eb + 255) / 256, 256, 0, stream>>>(eb, Eb, cnt, 0);
    k_hist<<<(Ev + 255) / 256, 256, 0, stream>>>(ev, Ev, cnt, N);
    k_hist<<<(Ec + 255) / 256, 256, 0, stream>>>(ec, Ec, cnt, 2 * N);
    k_scan_a<<<nScanBlocks, 256, 0, stream>>>(cnt, ptr_, bsum, M);
    k_scan_b<<<1, 256, 0, stream>>>(bsum, nScanBlocks);
    k_scan_c<<<(M + 255) / 256, 256, 0, stream>>>(ptr_, bsum, cur, M, Etot);
    k_dinv<<<(N + 255) / 256, 256, 0, stream>>>(cnt, dinv, N);
    k_scatter<<<(Eb + 255) / 256, 256, 0, stream>>>(eb, Eb, cur, cidx, 0);
    k_scatter<<<(Ev + 255) / 256, 256, 0, stream>>>(ev, Ev, cur, cidx, N);
    k_scatter<<<(Ec + 255) / 256, 256, 0, stream>>>(ec, Ec, cur, cidx, 2 * N);

    // --- conversions + GEMM ---
    k_convert_w<<<(1536 * 512 + 255) / 256, 256, 0, stream>>>(Wb, Wv, Wc, Wf);
    {
        size_t total = Npad * 512, valid = (size_t)N * 512;
        k_conv_x<<<(int)((total / 4 + 255) / 256), 256, 0, stream>>>(x, xf, valid, total);
    }
    k_gemm_f<<<dim3(nbm, 12), 256, 0, stream>>>(xf, Wf, Ybv, Ycf);

    // --- fused gather ---
    k_gather<<<(N + 3) / 4, 256, 0, stream>>>(ptr_, cidx, dinv, Ybv, Ycf, att, bias, out, N);
}

// Round 7
// 478.401 us; speedup vs baseline: 35.0123x; 1.0420x over previous
//
#include <hip/hip_runtime.h>
#include <stdint.h>

typedef _Float16 f16x8 __attribute__((ext_vector_type(8)));
typedef _Float16 f16x2 __attribute__((ext_vector_type(2)));
typedef float f32x4 __attribute__((ext_vector_type(4)));

__device__ __forceinline__ unsigned short f2h(float f) {
    _Float16 h = (_Float16)f;
    return __builtin_bit_cast(unsigned short, h);
}
__device__ __forceinline__ float h2f(unsigned short s) {
    _Float16 h = __builtin_bit_cast(_Float16, s);
    return (float)h;
}

__device__ __forceinline__ void gload16(const void* g, void* lds) {
    __builtin_amdgcn_global_load_lds(
        (const __attribute__((address_space(1))) void*)g,
        (__attribute__((address_space(3))) void*)lds, 16, 0, 0);
}

#if __has_builtin(__builtin_amdgcn_fdot2)
__device__ __forceinline__ float dot2(f16x2 a, f16x2 b, float c) {
    return __builtin_amdgcn_fdot2(a, b, c, false);
}
#else
__device__ __forceinline__ float dot2(f16x2 a, f16x2 b, float c) {
    return c + (float)a[0] * (float)b[0] + (float)a[1] * (float)b[1];
}
#endif

// ---------------- W conversion: stack [W_bond; W_vin; W_vconn] as fp16 [1536][512]
__global__ __launch_bounds__(256) void k_convert_w(
    const float* __restrict__ Wb, const float* __restrict__ Wv,
    const float* __restrict__ Wc, unsigned short* __restrict__ Wf)
{
    int idx = blockIdx.x * 256 + threadIdx.x;
    if (idx >= 1536 * 512) return;
    int m = idx >> 9, k = idx & 511;
    float s;
    if (m < 512)       s = Wb[m * 512 + k];
    else if (m < 1024) s = Wv[(m - 512) * 512 + k];
    else               s = Wc[(m - 1024) * 512 + k];
    Wf[idx] = f2h(s);
}

// ---------------- x conversion: f32 -> fp16, zero-padded to Npad rows
__global__ __launch_bounds__(256) void k_conv_x(
    const float* __restrict__ x, unsigned short* __restrict__ xf,
    size_t valid, size_t total)
{
    size_t idx = ((size_t)blockIdx.x * 256 + threadIdx.x) * 4;
    if (idx >= total) return;
    ushort4 h;
    if (idx < valid) {
        float4 f = *(const float4*)(x + idx);
        h.x = f2h(f.x); h.y = f2h(f.y); h.z = f2h(f.z); h.w = f2h(f.w);
    } else {
        h.x = h.y = h.z = h.w = 0;
    }
    *(ushort4*)(xf + idx) = h;
}

// ---------------- CSR build (fused) ----------------
__global__ __launch_bounds__(256) void k_hist3(
    const int* __restrict__ eb, const int* __restrict__ ev, const int* __restrict__ ec,
    int Eb, int Ev, int Ec, int* __restrict__ cnt, int N)
{
    int i = blockIdx.x * 256 + threadIdx.x;
    if (i < Eb) atomicAdd(cnt + eb[i], 1);
    else if (i < Eb + Ev) atomicAdd(cnt + N + ev[i - Eb], 1);
    else if (i < Eb + Ev + Ec) atomicAdd(cnt + 2 * N + ec[i - Eb - Ev], 1);
}

__global__ __launch_bounds__(256) void k_scan_a(
    const int* __restrict__ cnt, int* __restrict__ ptr, int* __restrict__ bsum, int M)
{
    __shared__ int sh[256];
    int t = threadIdx.x;
    int base = blockIdx.x * 1024 + t * 4;
    int v[4];
    #pragma unroll
    for (int j = 0; j < 4; j++) v[j] = (base + j < M) ? cnt[base + j] : 0;
    int local = v[0] + v[1] + v[2] + v[3];
    sh[t] = local; __syncthreads();
    #pragma unroll
    for (int off = 1; off < 256; off <<= 1) {
        int x = (t >= off) ? sh[t - off] : 0;
        __syncthreads();
        sh[t] += x;
        __syncthreads();
    }
    int run = sh[t] - local;
    #pragma unroll
    for (int j = 0; j < 4; j++) {
        if (base + j < M) ptr[base + j] = run;
        run += v[j];
    }
    if (t == 255) bsum[blockIdx.x] = sh[255];
}

__global__ __launch_bounds__(256) void k_scan_b(int* __restrict__ bsum, int nb)
{
    __shared__ int sh[256];
    int t = threadIdx.x;
    int v = (t < nb) ? bsum[t] : 0;
    sh[t] = v; __syncthreads();
    #pragma unroll
    for (int off = 1; off < 256; off <<= 1) {
        int x = (t >= off) ? sh[t - off] : 0;
        __syncthreads();
        sh[t] += x;
        __syncthreads();
    }
    if (t < nb) bsum[t] = sh[t] - v;
}

// scan C + dinv fused
__global__ __launch_bounds__(256) void k_scan_c(
    int* __restrict__ ptr, const int* __restrict__ bsum, int* __restrict__ cur,
    const int* __restrict__ cnt, float* __restrict__ dinv,
    int M, int N, int total)
{
    int idx = blockIdx.x * 256 + threadIdx.x;
    if (idx < M) {
        int p = ptr[idx] + bsum[idx >> 10];
        ptr[idx] = p;
        cur[idx] = p;
        if (idx < N) dinv[idx] = rsqrtf((float)(cnt[idx] + 1));
    }
    if (idx == 0) ptr[M] = total;
}

__global__ __launch_bounds__(256) void k_scatter3(
    const int* __restrict__ eb, const int* __restrict__ ev, const int* __restrict__ ec,
    int Eb, int Ev, int Ec, int* __restrict__ cur, int* __restrict__ cidx, int N)
{
    int i = blockIdx.x * 256 + threadIdx.x;
    const int* e; int il, off, E;
    if (i < Eb) { e = eb; il = i; off = 0; E = Eb; }
    else if (i < Eb + Ev) { e = ev; il = i - Eb; off = N; E = Ev; }
    else if (i < Eb + Ev + Ec) { e = ec; il = i - Eb - Ev; off = 2 * N; E = Ec; }
    else return;
    int r = e[il], c = e[E + il];
    int pos = atomicAdd(cur + off + r, 1);
    cidx[pos] = c;
}

// ---------------- UNIFIED fp16 GEMM: Y[n,m] = sum_k x[n,k] * Wst[m,k]
// 1D grid with XCD-aware bijective swizzle: the 12 bn-tiles sharing one
// A-tile land on the same XCD (consecutive ids differing in bn are 8 apart
// -> same id%8 -> same XCD under HW round-robin) so A is L2-resident.
// bn 0..7 -> Ybv fp16 [Npad][1024]; bn 8..11 -> Ycf fp16 [Npad][512]
__global__ __launch_bounds__(256) void k_gemm_f(
    const unsigned short* __restrict__ xf, const unsigned short* __restrict__ Wf,
    unsigned short* __restrict__ Ybv, unsigned short* __restrict__ Ycf)
{
    __shared__ uint4 As[1024];
    __shared__ uint4 Bs[1024];

    const int id = blockIdx.x;
    const int xcd = id & 7;
    const int jj = id >> 3;
    const int bn = jj % 12;
    const int bm = xcd + 8 * (jj / 12);

    const int t = threadIdx.x;
    const int lane = t & 63;
    const int w = t >> 6;
    const int wr = w >> 1, wc = w & 1;
    const int rA = lane >> 3;     // row within 8-row segment
    const int cs = lane & 7;      // LDS chunk slot

    f32x4 acc[4][4];
    #pragma unroll
    for (int i = 0; i < 4; i++)
        #pragma unroll
        for (int j = 0; j < 4; j++) acc[i][j] = (f32x4){0.f, 0.f, 0.f, 0.f};

    const size_t baseA = (size_t)bm * 128 * 512;
    const size_t baseB = (size_t)bn * 128 * 512;

    for (int kt = 0; kt < 512; kt += 64) {
        #pragma unroll
        for (int j = 0; j < 4; j++) {
            int seg = w * 4 + j;
            int r = seg * 8 + rA;
            int cg = cs ^ (r & 7);
            gload16(xf + baseA + (size_t)r * 512 + kt + cg * 8, &As[seg * 64]);
            gload16(Wf + baseB + (size_t)r * 512 + kt + cg * 8, &Bs[seg * 64]);
        }
        __syncthreads();
        #pragma unroll
        for (int kk = 0; kk < 2; kk++) {
            f16x8 a[4], b[4];
            #pragma unroll
            for (int ni = 0; ni < 4; ni++) {
                int ar = wr * 64 + ni * 16 + (lane & 15);
                int k8 = kk * 4 + (lane >> 4);
                a[ni] = __builtin_bit_cast(f16x8, As[ar * 8 + (k8 ^ (ar & 7))]);
            }
            #pragma unroll
            for (int mi = 0; mi < 4; mi++) {
                int br = wc * 64 + mi * 16 + (lane & 15);
                int k8 = kk * 4 + (lane >> 4);
                b[mi] = __builtin_bit_cast(f16x8, Bs[br * 8 + (k8 ^ (br & 7))]);
            }
            #pragma unroll
            for (int mi = 0; mi < 4; mi++)
                #pragma unroll
                for (int ni = 0; ni < 4; ni++)
                    acc[mi][ni] = __builtin_amdgcn_mfma_f32_16x16x32_f16(
                        a[ni], b[mi], acc[mi][ni], 0, 0, 0);
        }
        __syncthreads();
    }

    const int nbase = bm * 128 + wr * 64 + (lane >> 4) * 4;
    const int mbase = bn * 128 + wc * 64 + (lane & 15);
    if (bn < 8) {
        #pragma unroll
        for (int mi = 0; mi < 4; mi++) {
            int m = mbase + mi * 16;
            #pragma unroll
            for (int ni = 0; ni < 4; ni++) {
                int n0 = nbase + ni * 16;
                #pragma unroll
                for (int j = 0; j < 4; j++)
                    Ybv[(size_t)(n0 + j) * 1024 + m] = f2h(acc[mi][ni][j]);
            }
        }
    } else {
        #pragma unroll
        for (int mi = 0; mi < 4; mi++) {
            int m = mbase + mi * 16 - 1024;
            #pragma unroll
            for (int ni = 0; ni < 4; ni++) {
                int n0 = nbase + ni * 16;
                #pragma unroll
                for (int j = 0; j < 4; j++)
                    Ycf[(size_t)(n0 + j) * 512 + m] = f2h(acc[mi][ni][j]);
            }
        }
    }
}

// ---------------- fused gather: one wave per node, chunk-4 pipelined
__device__ __forceinline__ void acc_h8(float* a, uint4 v, float s) {
    a[0] += s * h2f((unsigned short)(v.x & 0xffff));
    a[1] += s * h2f((unsigned short)(v.x >> 16));
    a[2] += s * h2f((unsigned short)(v.y & 0xffff));
    a[3] += s * h2f((unsigned short)(v.y >> 16));
    a[4] += s * h2f((unsigned short)(v.z & 0xffff));
    a[5] += s * h2f((unsigned short)(v.z >> 16));
    a[6] += s * h2f((unsigned short)(v.w & 0xffff));
    a[7] += s * h2f((unsigned short)(v.w >> 16));
}
__device__ __forceinline__ float dot8(const f16x2* ph, uint4 u) {
    float d = 0.f;
    d = dot2(ph[0], __builtin_bit_cast(f16x2, u.x), d);
    d = dot2(ph[1], __builtin_bit_cast(f16x2, u.y), d);
    d = dot2(ph[2], __builtin_bit_cast(f16x2, u.z), d);
    d = dot2(ph[3], __builtin_bit_cast(f16x2, u.w), d);
    return d;
}

__global__ __launch_bounds__(256) void k_gather(
    const int* __restrict__ ptr, const int* __restrict__ cidx,
    const float* __restrict__ dinv,
    const unsigned short* __restrict__ Ybv, const unsigned short* __restrict__ Ycf,
    const float* __restrict__ att, const float* __restrict__ bias,
    float* __restrict__ out, int N)
{
    int node = blockIdx.x * 4 + (threadIdx.x >> 6);
    if (node >= N) return;
    int lane = threadIdx.x & 63;

    float a[8];
    {
        const float4* bp = (const float4*)(bias + lane * 8);
        float4 q0 = bp[0], q1 = bp[1];
        a[0] = q0.x; a[1] = q0.y; a[2] = q0.z; a[3] = q0.w;
        a[4] = q1.x; a[5] = q1.y; a[6] = q1.z; a[7] = q1.w;
    }

    float di = dinv[node];
    // self loop (bond)
    {
        uint4 v = *((const uint4*)(Ybv + (size_t)node * 1024) + lane);
        acc_h8(a, v, di * di);
    }
    // bond edges, chunk-4 pipelined
    {
        int e0 = ptr[node], e1 = ptr[node + 1];
        int e = e0;
        for (; e + 4 <= e1; e += 4) {
            int c0 = cidx[e], c1 = cidx[e + 1], c2 = cidx[e + 2], c3 = cidx[e + 3];
            uint4 v0 = *((const uint4*)(Ybv + (size_t)c0 * 1024) + lane);
            uint4 v1 = *((const uint4*)(Ybv + (size_t)c1 * 1024) + lane);
            uint4 v2 = *((const uint4*)(Ybv + (size_t)c2 * 1024) + lane);
            uint4 v3 = *((const uint4*)(Ybv + (size_t)c3 * 1024) + lane);
            float n0 = di * dinv[c0], n1 = di * dinv[c1];
            float n2 = di * dinv[c2], n3 = di * dinv[c3];
            acc_h8(a, v0, n0); acc_h8(a, v1, n1);
            acc_h8(a, v2, n2); acc_h8(a, v3, n3);
        }
        for (; e < e1; ++e) {
            int c = cidx[e];
            uint4 v = *((const uint4*)(Ybv + (size_t)c * 1024) + lane);
            acc_h8(a, v, di * dinv[c]);
        }
    }
    // vin edges (mean), chunk-4
    {
        int e0 = ptr[N + node], e1 = ptr[N + node + 1];
        float vsc = 1.0f / (float)((e1 - e0) > 1 ? (e1 - e0) : 1);
        int e = e0;
        for (; e + 4 <= e1; e += 4) {
            int c0 = cidx[e], c1 = cidx[e + 1], c2 = cidx[e + 2], c3 = cidx[e + 3];
            uint4 v0 = *((const uint4*)(Ybv + (size_t)c0 * 1024 + 512) + lane);
            uint4 v1 = *((const uint4*)(Ybv + (size_t)c1 * 1024 + 512) + lane);
            uint4 v2 = *((const uint4*)(Ybv + (size_t)c2 * 1024 + 512) + lane);
            uint4 v3 = *((const uint4*)(Ybv + (size_t)c3 * 1024 + 512) + lane);
            acc_h8(a, v0, vsc); acc_h8(a, v1, vsc);
            acc_h8(a, v2, vsc); acc_h8(a, v3, vsc);
        }
        for (; e < e1; ++e) {
            int c = cidx[e];
            uint4 v = *((const uint4*)(Ybv + (size_t)c * 1024 + 512) + lane);
            acc_h8(a, v, vsc);
        }
    }
    // conn edges (sigmoid dot attention), chunk-4, packed fdot2
    {
        int e0 = ptr[2 * N + node], e1 = ptr[2 * N + node + 1];
        if (e0 < e1) {
            const float4* ap = (const float4*)att + lane * 2;
            float4 t0 = ap[0], t1 = ap[1];
            float yr[8];
            {
                uint4 u = *((const uint4*)(Ycf + (size_t)node * 512) + lane);
                yr[0] = h2f((unsigned short)(u.x & 0xffff));
                yr[1] = h2f((unsigned short)(u.x >> 16));
                yr[2] = h2f((unsigned short)(u.y & 0xffff));
                yr[3] = h2f((unsigned short)(u.y >> 16));
                yr[4] = h2f((unsigned short)(u.z & 0xffff));
                yr[5] = h2f((unsigned short)(u.z >> 16));
                yr[6] = h2f((unsigned short)(u.w & 0xffff));
                yr[7] = h2f((unsigned short)(u.w >> 16));
            }
            f16x2 ph[4];
            ph[0] = (f16x2){(_Float16)(yr[0] * t0.x * t0.x), (_Float16)(yr[1] * t0.y * t0.y)};
            ph[1] = (f16x2){(_Float16)(yr[2] * t0.z * t0.z), (_Float16)(yr[3] * t0.w * t0.w)};
            ph[2] = (f16x2){(_Float16)(yr[4] * t1.x * t1.x), (_Float16)(yr[5] * t1.y * t1.y)};
            ph[3] = (f16x2){(_Float16)(yr[6] * t1.z * t1.z), (_Float16)(yr[7] * t1.w * t1.w)};
            int e = e0;
            for (; e + 4 <= e1; e += 4) {
                int c0 = cidx[e], c1 = cidx[e + 1], c2 = cidx[e + 2], c3 = cidx[e + 3];
                uint4 u0 = *((const uint4*)(Ycf + (size_t)c0 * 512) + lane);
                uint4 u1 = *((const uint4*)(Ycf + (size_t)c1 * 512) + lane);
                uint4 u2 = *((const uint4*)(Ycf + (size_t)c2 * 512) + lane);
                uint4 u3 = *((const uint4*)(Ycf + (size_t)c3 * 512) + lane);
                float d0 = dot8(ph, u0);
                float d1 = dot8(ph, u1);
                float d2 = dot8(ph, u2);
                float d3 = dot8(ph, u3);
                #pragma unroll
                for (int off = 32; off > 0; off >>= 1) {
                    d0 += __shfl_xor(d0, off);
                    d1 += __shfl_xor(d1, off);
                    d2 += __shfl_xor(d2, off);
                    d3 += __shfl_xor(d3, off);
                }
                float al0 = 1.0f / (1.0f + expf(-d0));
                float al1 = 1.0f / (1.0f + expf(-d1));
                float al2 = 1.0f / (1.0f + expf(-d2));
                float al3 = 1.0f / (1.0f + expf(-d3));
                acc_h8(a, u0, al0); acc_h8(a, u1, al1);
                acc_h8(a, u2, al2); acc_h8(a, u3, al3);
            }
            for (; e < e1; ++e) {
                int c = cidx[e];
                uint4 u = *((const uint4*)(Ycf + (size_t)c * 512) + lane);
                float dot = dot8(ph, u);
                #pragma unroll
                for (int off = 32; off > 0; off >>= 1) dot += __shfl_xor(dot, off);
                float alpha = 1.0f / (1.0f + expf(-dot));
                acc_h8(a, u, alpha);
            }
        }
    }
    float4 o0 = make_float4(a[0], a[1], a[2], a[3]);
    float4 o1 = make_float4(a[4], a[5], a[6], a[7]);
    float4* dst = (float4*)(out + (size_t)node * 512 + lane * 8);
    dst[0] = o0; dst[1] = o1;
}

extern "C" void kernel_launch(void* const* d_in, const int* in_sizes, int n_in,
                              void* d_out, int out_size, void* d_ws, size_t ws_size,
                              hipStream_t stream) {
    const float* x    = (const float*)d_in[0];
    const int*   eb   = (const int*)d_in[1];
    const int*   ev   = (const int*)d_in[2];
    const int*   ec   = (const int*)d_in[3];
    const float* Wb   = (const float*)d_in[4];
    const float* Wv   = (const float*)d_in[5];
    const float* Wc   = (const float*)d_in[6];
    const float* att  = (const float*)d_in[7];
    const float* bias = (const float*)d_in[8];
    float* out = (float*)d_out;

    const int N  = in_sizes[0] / 512;
    const int Eb = in_sizes[1] / 2;
    const int Ev = in_sizes[2] / 2;
    const int Ec = in_sizes[3] / 2;
    const int Etot = Eb + Ev + Ec;
    // nbm rounded up to multiple of 8 so the XCD swizzle is bijective
    const int nbm = (((N + 127) / 128 + 7) / 8) * 8;
    const size_t Npad = (size_t)nbm * 128;
    const int M = 3 * N;
    const int nScanBlocks = (M + 1023) / 1024;

    char* p = (char*)d_ws;
    unsigned short* Ybv = (unsigned short*)p; p += Npad * 1024 * 2;  // bond|vin fp16
    unsigned short* Ycf = (unsigned short*)p; p += Npad * 512 * 2;   // vconn fp16
    unsigned short* Wf  = (unsigned short*)p; p += (size_t)1536 * 512 * 2;
    unsigned short* xf  = (unsigned short*)p; p += Npad * 512 * 2;
    int* cnt  = (int*)p; p += ((size_t)M * 4 + 255) & ~(size_t)255;
    int* ptr_ = (int*)p; p += ((size_t)(M + 1) * 4 + 255) & ~(size_t)255;
    int* cur  = (int*)p; p += ((size_t)M * 4 + 255) & ~(size_t)255;
    int* bsum = (int*)p; p += 256 * 4;
    int* cidx = (int*)p; p += ((size_t)Etot * 4 + 255) & ~(size_t)255;
    float* dinv = (float*)p; p += ((size_t)N * 4 + 255) & ~(size_t)255;

    // --- CSR build ---
    hipMemsetAsync(cnt, 0, (size_t)M * 4, stream);
    k_hist3<<<(Etot + 255) / 256, 256, 0, stream>>>(eb, ev, ec, Eb, Ev, Ec, cnt, N);
    k_scan_a<<<nScanBlocks, 256, 0, stream>>>(cnt, ptr_, bsum, M);
    k_scan_b<<<1, 256, 0, stream>>>(bsum, nScanBlocks);
    k_scan_c<<<(M + 255) / 256, 256, 0, stream>>>(ptr_, bsum, cur, cnt, dinv, M, N, Etot);
    k_scatter3<<<(Etot + 255) / 256, 256, 0, stream>>>(eb, ev, ec, Eb, Ev, Ec, cur, cidx, N);

    // --- conversions + GEMM ---
    k_convert_w<<<(1536 * 512 + 255) / 256, 256, 0, stream>>>(Wb, Wv, Wc, Wf);
    {
        size_t total = Npad * 512, valid = (size_t)N * 512;
        k_conv_x<<<(int)((total / 4 + 255) / 256), 256, 0, stream>>>(x, xf, valid, total);
    }
    k_gemm_f<<<nbm * 12, 256, 0, stream>>>(xf, Wf, Ybv, Ycf);

    // --- fused gather ---
    k_gather<<<(N + 3) / 4, 256, 0, stream>>>(ptr_, cidx, dinv, Ybv, Ycf, att, bias, out, N);
}